// Round 1
// baseline (35982.788 us; speedup 1.0000x reference)
//
#include <hip/hip_runtime.h>

#define EPSV 1e-5f

__device__ __forceinline__ float b2f(unsigned short u) {
  unsigned int x = ((unsigned int)u) << 16;
  return __uint_as_float(x);
}
__device__ __forceinline__ unsigned short f2b(float f) {
  unsigned int x = __float_as_uint(f);
  unsigned int r = (x + 0x7FFFu + ((x >> 16) & 1u)) >> 16;
  return (unsigned short)r;
}
__device__ __forceinline__ float sigm(float x) { return 1.0f / (1.0f + expf(-x)); }

// ---------------- dtype detection ----------------
// flags[0]: 1 = float inputs are f32 on device, 0 = bf16
// flags[1]: mask dtype: 0=u8, 1=i32, 2=f32, 3=bf16
__global__ void k_detect(const void* __restrict__ embp, const void* __restrict__ zmp,
                         int* __restrict__ flags) {
  __shared__ int sh[4];
  int tid = threadIdx.x;
  if (tid < 4) sh[tid] = 0;
  __syncthreads();
  const unsigned short* u = (const unsigned short*)embp;
  int bad = 0;
  for (int i = tid; i < 4096; i += 256) {
    float f = fabsf(b2f(u[i]));
    if (!(f < 1e10f)) bad = 1;
  }
  if (bad) atomicAdd(&sh[3], 1);
  const unsigned char* p = (const unsigned char*)zmp;
  int codd = 0, c0 = 0, c1v = 0;
  for (int i = tid; i < 65536; i += 256) {
    unsigned char v = p[i];
    if (v) {
      if (i & 1) codd++;
      if ((i & 3) == 0) c0++;
      if (v == 1) c1v++;
    }
  }
  atomicAdd(&sh[0], codd); atomicAdd(&sh[1], c0); atomicAdd(&sh[2], c1v);
  __syncthreads();
  if (tid == 0) {
    flags[0] = sh[3] ? 1 : 0;
    int mode;
    if (sh[0] == 0) mode = 1;        // only byte0-of-word nonzero -> int32
    else if (sh[2] > 0) mode = 0;    // 0x01 bytes -> u8 bool
    else if (sh[1] == 0) mode = 2;   // byte0 always zero -> f32 (00 00 80 3F)
    else mode = 3;                   // bf16 (80 3F pairs)
    flags[1] = mode;
  }
}

__global__ void k_cvt(const void* __restrict__ src, float* __restrict__ dst, int n,
                      const int* __restrict__ flags) {
  int i = blockIdx.x * 256 + threadIdx.x;
  if (i >= n) return;
  if (flags[0]) dst[i] = ((const float*)src)[i];
  else dst[i] = b2f(((const unsigned short*)src)[i]);
}

__device__ __forceinline__ bool mask_at(const void* p, size_t i, int mode) {
  switch (mode) {
    case 0: return ((const unsigned char*)p)[i] != 0;
    case 1: return ((const int*)p)[i] != 0;
    case 2: return ((const float*)p)[i] != 0.0f;
    default: return ((const unsigned short*)p)[i] != 0;
  }
}

// ---------------- embedding ----------------
__global__ void k_embed(const int* __restrict__ ph, const float* __restrict__ emb,
                        float* __restrict__ X) {
  int bl = blockIdx.x;
  int p = ph[bl];
  X[(size_t)bl * 256 + threadIdx.x] = emb[(size_t)p * 256 + threadIdx.x];
}

// ---------------- k=3 conv, E=256 -> E=256, SAME ----------------
// block: (b, 4 consecutive l); threads = co
__global__ __launch_bounds__(256) void k_conv3(const float* __restrict__ X,
                                               const float* __restrict__ Wc,
                                               float* __restrict__ Y) {
  __shared__ float xs[6 * 256];
  int blk = blockIdx.x;
  int b = blk >> 6, l0 = (blk & 63) * 4;
  for (int i = threadIdx.x; i < 6 * 256; i += 256) {
    int dl = i >> 8, ci = i & 255;
    int ll = l0 - 1 + dl;
    xs[i] = (ll >= 0 && ll < 256) ? X[(size_t)(b * 256 + ll) * 256 + ci] : 0.0f;
  }
  __syncthreads();
  int co = threadIdx.x;
  float acc[4] = {0.f, 0.f, 0.f, 0.f};
  for (int i = 0; i < 768; ++i) {
    int d = i >> 8, ci = i & 255;
    float wv = Wc[(size_t)i * 256 + co];
#pragma unroll
    for (int j = 0; j < 4; ++j) acc[j] += xs[(d + j) * 256 + ci] * wv;
  }
#pragma unroll
  for (int j = 0; j < 4; ++j) Y[(size_t)(b * 256 + l0 + j) * 256 + co] = acc[j];
}

// ---------------- per-channel mean/var (batch-stat BN) ----------------
__global__ __launch_bounds__(256) void k_colstats(const float* __restrict__ X, int R, int C,
                                                  float* __restrict__ st) {
  int c = blockIdx.x;
  float s = 0.f, q = 0.f;
  for (int r = threadIdx.x; r < R; r += 256) {
    float v = X[(size_t)r * C + c];
    s += v; q += v * v;
  }
  __shared__ float rs_[256], rq_[256];
  rs_[threadIdx.x] = s; rq_[threadIdx.x] = q;
  __syncthreads();
  for (int k = 128; k > 0; k >>= 1) {
    if (threadIdx.x < k) { rs_[threadIdx.x] += rs_[threadIdx.x + k]; rq_[threadIdx.x] += rq_[threadIdx.x + k]; }
    __syncthreads();
  }
  if (threadIdx.x == 0) {
    float m = rs_[0] / R;
    st[c] = m;
    st[C + c] = rq_[0] / R - m * m;
  }
}

template <int ACT>  // 0 = relu, 1 = tanh
__global__ void k_bnact(const float* __restrict__ X, float* __restrict__ Y,
                        const float* __restrict__ st, const float* __restrict__ sc,
                        const float* __restrict__ of, int Cmask, int n) {
  int i = blockIdx.x * 256 + threadIdx.x;
  if (i >= n) return;
  int C = Cmask + 1;
  int c = i & Cmask;
  float m = st[c], v = st[C + c];
  float y = (X[i] - m) * rsqrtf(v + EPSV) * sc[c] + of[c];
  Y[i] = ACT ? tanhf(y) : fmaxf(y, 0.0f);
}

// ---------------- generic GEMM: C[M,N] = A[M,K]f32 @ B[K,N]f32 (+bias) ----------------
template <int OBF>  // 1 -> bf16 output
__global__ __launch_bounds__(256) void k_gemm(const float* __restrict__ Ap,
                                              const float* __restrict__ Bp,
                                              const float* __restrict__ bias,
                                              void* __restrict__ Cp, int M, int K, int N) {
  __shared__ float al[16 * 768];
  int row0 = blockIdx.x * 16;
  int c = blockIdx.y * 256 + threadIdx.x;
  for (int i = threadIdx.x; i < 16 * K; i += 256) al[i] = Ap[(size_t)row0 * K + i];
  __syncthreads();
  float acc[16];
  float bv = bias ? bias[c] : 0.0f;
#pragma unroll
  for (int j = 0; j < 16; ++j) acc[j] = bv;
  for (int k = 0; k < K; ++k) {
    float b = Bp[(size_t)k * N + c];
#pragma unroll
    for (int j = 0; j < 16; ++j) acc[j] += al[j * K + k] * b;
  }
  if (OBF) {
    unsigned short* C = (unsigned short*)Cp;
#pragma unroll
    for (int j = 0; j < 16; ++j) C[(size_t)(row0 + j) * N + c] = f2b(acc[j]);
  } else {
    float* C = (float*)Cp;
#pragma unroll
    for (int j = 0; j < 16; ++j) C[(size_t)(row0 + j) * N + c] = acc[j];
  }
}

// ---------------- duration cumsum -> mid positions ----------------
__global__ void k_cumsum(const float* __restrict__ dur, float* __restrict__ mid) {
  int b = threadIdx.x;
  if (b >= 16) return;
  float run = 0.f;
  for (int l = 0; l < 256; ++l) {
    float d = dur[b * 256 + l];
    run += d;
    mid[b * 256 + l] = run - 0.5f * d;
  }
}

// ---------------- persistent bi-LSTM encoder ----------------
// grid 128: wg<64 fwd, >=64 bwd. Each wg owns 4 h-cols (of 256). 256 threads.
__global__ __launch_bounds__(256) void k_enc_lstm(const float* __restrict__ GFp,
                                                  const float* __restrict__ GBp,
                                                  const float* __restrict__ Wf,
                                                  const float* __restrict__ Wb,
                                                  float* __restrict__ enc,
                                                  const int* __restrict__ lengths,
                                                  unsigned int* __restrict__ cnt) {
  const int tid = threadIdx.x;
  const int wg = blockIdx.x;
  const int dir = wg >> 6;
  const int w = wg & 63;
  const float* Gpre = dir ? GBp : GFp;
  const float* W = dir ? Wb : Wf;
  unsigned int* c_self = cnt + dir * 256;

  __shared__ float hs[16 * 264];
  __shared__ float wh[16 * 264];
  __shared__ float part[16 * 257];
  __shared__ float gl[256];
  __shared__ float cst[64];
  __shared__ int rs[16];

  for (int i = tid; i < 16 * 256; i += 256) {
    int gc = i >> 8, k = i & 255;
    int g = gc >> 2, j = gc & 3;
    wh[gc * 264 + k] = W[(size_t)(256 + k) * 1024 + g * 256 + (w * 4 + j)];
  }
  if (tid < 64) cst[tid] = 0.0f;
  __syncthreads();

  const int og = tid >> 4, s = tid & 15;
  const int bq = og >> 2, jj = og & 3;

  for (int t = 0; t < 256; ++t) {
    const int l = dir ? (255 - t) : t;
    if (tid < 16) rs[tid] = (dir == 1) && (l >= lengths[tid] - 1);
    if (t > 0 && tid == 0) {
      unsigned int gcount = 0;
      while (__hip_atomic_load(c_self + (t - 1), __ATOMIC_RELAXED, __HIP_MEMORY_SCOPE_AGENT) < 64u) {
        __builtin_amdgcn_s_sleep(4);
        if (++gcount > (1u << 16)) break;
      }
      __threadfence();
    }
    __syncthreads();
    if (t > 0) {
      const int lprev = dir ? (l + 1) : (l - 1);
      for (int i = tid; i < 16 * 256; i += 256) {
        int b = i >> 8, k = i & 255;
        float v = enc[(size_t)(b * 256 + lprev) * 512 + dir * 256 + k];
        if (rs[b]) v = 0.0f;
        hs[b * 264 + k] = v;
      }
    }
    __syncthreads();

    float acc[4][4];
#pragma unroll
    for (int a = 0; a < 4; ++a) { acc[a][0] = 0; acc[a][1] = 0; acc[a][2] = 0; acc[a][3] = 0; }
    if (t > 0) {
      const int b0 = bq * 4;
#pragma unroll 4
      for (int i = 0; i < 16; ++i) {
        int k = i * 16 + s;
        float h0 = hs[(b0 + 0) * 264 + k];
        float h1 = hs[(b0 + 1) * 264 + k];
        float h2 = hs[(b0 + 2) * 264 + k];
        float h3 = hs[(b0 + 3) * 264 + k];
#pragma unroll
        for (int g = 0; g < 4; ++g) {
          float wv = wh[(g * 4 + jj) * 264 + k];
          acc[0][g] += h0 * wv; acc[1][g] += h1 * wv;
          acc[2][g] += h2 * wv; acc[3][g] += h3 * wv;
        }
      }
    }
#pragma unroll
    for (int a = 0; a < 4; ++a)
#pragma unroll
      for (int g = 0; g < 4; ++g)
        part[s * 257 + ((bq * 4 + a) * 16 + jj * 4 + g)] = acc[a][g];
    __syncthreads();
    {
      int b = tid >> 4, j = (tid >> 2) & 3, g = tid & 3;
      float sum = 0.0f;
      if (t > 0) {
#pragma unroll
        for (int ss = 0; ss < 16; ++ss) sum += part[ss * 257 + tid];
      }
      sum += Gpre[(size_t)(b * 256 + l) * 1024 + g * 256 + (w * 4 + j)];
      gl[tid] = sum;
    }
    __syncthreads();
    if (tid < 64) {
      int b = tid >> 2, j = tid & 3;
      float gi = gl[b * 16 + j * 4 + 0];
      float gg = gl[b * 16 + j * 4 + 1];
      float gf = gl[b * 16 + j * 4 + 2];
      float go = gl[b * 16 + j * 4 + 3];
      float c = cst[tid];
      if (t == 0 || rs[b]) c = 0.0f;
      c = sigm(gf + 1.0f) * c + sigm(gi) * tanhf(gg);
      float h = sigm(go) * tanhf(c);
      cst[tid] = c;
      enc[(size_t)(b * 256 + l) * 512 + dir * 256 + (w * 4 + j)] = h;
    }
    __threadfence();
    __syncthreads();
    if (tid == 0)
      __hip_atomic_fetch_add(c_self + t, 1u, __ATOMIC_RELEASE, __HIP_MEMORY_SCOPE_AGENT);
  }
}

// ---------------- Gaussian-softmax upsampling ----------------
__global__ __launch_bounds__(256) void k_upsample(const float* __restrict__ mid,
                                                  const float* __restrict__ enc,
                                                  float* __restrict__ cond) {
  int blk = blockIdx.x;
  int b = blk >> 5, t0 = (blk & 31) * 16;
  int tid = threadIdx.x;
  __shared__ float wls[16][256];
  __shared__ float red[256];
  float mp = mid[b * 256 + tid];
  for (int tt = 0; tt < 16; ++tt) {
    float tpos = (float)(t0 + tt);
    float d = mp - tpos;
    float d2 = d * d * 0.1f;
    red[tid] = d2; __syncthreads();
    for (int k = 128; k > 0; k >>= 1) { if (tid < k) red[tid] = fminf(red[tid], red[tid + k]); __syncthreads(); }
    float mn = red[0]; __syncthreads();
    float e = expf(mn - d2);
    red[tid] = e; __syncthreads();
    for (int k = 128; k > 0; k >>= 1) { if (tid < k) red[tid] += red[tid + k]; __syncthreads(); }
    float sum = red[0]; __syncthreads();
    wls[tt][tid] = e / sum;
  }
  __syncthreads();
  float a0[16], a1[16];
#pragma unroll
  for (int i = 0; i < 16; ++i) { a0[i] = 0; a1[i] = 0; }
  for (int l = 0; l < 256; ++l) {
    float e0 = enc[(size_t)(b * 256 + l) * 512 + tid];
    float e1 = enc[(size_t)(b * 256 + l) * 512 + 256 + tid];
#pragma unroll
    for (int tt = 0; tt < 16; ++tt) { float wv = wls[tt][l]; a0[tt] += wv * e0; a1[tt] += wv * e1; }
  }
  for (int tt = 0; tt < 16; ++tt) {
    cond[(size_t)(b * 512 + t0 + tt) * 512 + tid] = a0[tt];
    cond[(size_t)(b * 512 + t0 + tt) * 512 + 256 + tid] = a1[tt];
  }
}

__global__ void k_concat(const float* __restrict__ cond, const float* __restrict__ p,
                         float* __restrict__ din) {
  size_t i = (size_t)blockIdx.x * 256 + threadIdx.x;
  int r = (int)(i / 768);
  int c = (int)(i % 768);
  din[i] = (c < 512) ? cond[(size_t)r * 512 + c] : p[(size_t)r * 256 + (c - 512)];
}

// ---------------- persistent 2-layer zoneout LSTM decoder ----------------
#define LDHD 1032
__global__ __launch_bounds__(256) void k_dec_lstm(
    const unsigned short* __restrict__ D1x, const unsigned short* __restrict__ D2x,
    const float* __restrict__ W1, const float* __restrict__ W2,
    const void* __restrict__ zh1, const void* __restrict__ zc1,
    const void* __restrict__ zh2, const void* __restrict__ zc2,
    float* __restrict__ h1c, float* __restrict__ h1n,
    float* __restrict__ h2c, float* __restrict__ h2n,
    unsigned int* __restrict__ cnt1, unsigned int* __restrict__ cnt2,
    const int* __restrict__ flags) {
  const int tid = threadIdx.x;
  const int wg = blockIdx.x;
  const bool isL2 = wg >= 128;
  const int w = isL2 ? (wg - 128) : wg;

  __shared__ float hs[16 * LDHD];
  __shared__ float wh[16 * LDHD];
  __shared__ float part[16 * 257];
  __shared__ float gl[256];
  __shared__ float cst[64];

  const int mmode = flags[1];
  const int KK = isL2 ? 1024 : 512;
  const float* W = isL2 ? W2 : W1;

  for (int i = tid; i < 16 * KK; i += 256) {
    int gc = i / KK, k = i - gc * KK;
    int g = gc >> 2, j = gc & 3;
    wh[gc * LDHD + k] = W[(size_t)(768 + k) * 2048 + g * 512 + (w * 4 + j)];
  }
  if (tid < 64) cst[tid] = 0.0f;
  __syncthreads();

  const int og = tid >> 4, s = tid & 15;
  const int bq = og >> 2, jj = og & 3;
  const int SEGI = KK >> 4;

  const void* zh = isL2 ? zh2 : zh1;
  const void* zc = isL2 ? zc2 : zc1;
  const unsigned short* Dx = isL2 ? D2x : D1x;
  float* hN = isL2 ? h2n : h1n;
  float* hC = isL2 ? h2c : h1c;

  for (int t = 0; t < 512; ++t) {
    if (tid == 0) {
      unsigned int gcount = 0;
      if (isL2) {
        while (__hip_atomic_load(cnt1 + t, __ATOMIC_RELAXED, __HIP_MEMORY_SCOPE_AGENT) < 128u) {
          __builtin_amdgcn_s_sleep(4);
          if (++gcount > (1u << 16)) break;
        }
        if (t > 0) {
          gcount = 0;
          while (__hip_atomic_load(cnt2 + (t - 1), __ATOMIC_RELAXED, __HIP_MEMORY_SCOPE_AGENT) < 128u) {
            __builtin_amdgcn_s_sleep(4);
            if (++gcount > (1u << 16)) break;
          }
        }
      } else if (t > 0) {
        while (__hip_atomic_load(cnt1 + (t - 1), __ATOMIC_RELAXED, __HIP_MEMORY_SCOPE_AGENT) < 128u) {
          __builtin_amdgcn_s_sleep(4);
          if (++gcount > (1u << 16)) break;
        }
      }
      __threadfence();
    }
    __syncthreads();
    if (isL2) {
      for (int i = tid; i < 16 * 512; i += 256) {
        int b = i >> 9, k = i & 511;
        hs[b * LDHD + k] = h1n[(size_t)(t * 16 + b) * 512 + k];
      }
      for (int i = tid; i < 16 * 512; i += 256) {
        int b = i >> 9, k = i & 511;
        hs[b * LDHD + 512 + k] = (t > 0) ? h2c[(size_t)((t - 1) * 16 + b) * 512 + k] : 0.0f;
      }
    } else if (t > 0) {
      for (int i = tid; i < 16 * 512; i += 256) {
        int b = i >> 9, k = i & 511;
        hs[b * LDHD + k] = h1c[(size_t)((t - 1) * 16 + b) * 512 + k];
      }
    }
    __syncthreads();

    float acc[4][4];
#pragma unroll
    for (int a = 0; a < 4; ++a) { acc[a][0] = 0; acc[a][1] = 0; acc[a][2] = 0; acc[a][3] = 0; }
    const bool doDot = isL2 || (t > 0);
    if (doDot) {
      const int b0 = bq * 4;
      for (int i = 0; i < SEGI; ++i) {
        int k = i * 16 + s;
        float h0 = hs[(b0 + 0) * LDHD + k];
        float h1v = hs[(b0 + 1) * LDHD + k];
        float h2v = hs[(b0 + 2) * LDHD + k];
        float h3v = hs[(b0 + 3) * LDHD + k];
#pragma unroll
        for (int g = 0; g < 4; ++g) {
          float wv = wh[(g * 4 + jj) * LDHD + k];
          acc[0][g] += h0 * wv; acc[1][g] += h1v * wv;
          acc[2][g] += h2v * wv; acc[3][g] += h3v * wv;
        }
      }
    }
#pragma unroll
    for (int a = 0; a < 4; ++a)
#pragma unroll
      for (int g = 0; g < 4; ++g)
        part[s * 257 + ((bq * 4 + a) * 16 + jj * 4 + g)] = acc[a][g];
    __syncthreads();
    {
      int b = tid >> 4, j = (tid >> 2) & 3, g = tid & 3;
      float sum = 0.0f;
      if (doDot) {
#pragma unroll
        for (int ss = 0; ss < 16; ++ss) sum += part[ss * 257 + tid];
      }
      sum += b2f(Dx[((size_t)(b * 512 + t)) * 2048 + g * 512 + (w * 4 + j)]);
      gl[tid] = sum;
    }
    __syncthreads();
    if (tid < 64) {
      int b = tid >> 2, j = tid & 3;
      int colg = w * 4 + j;
      float gi = gl[b * 16 + j * 4 + 0];
      float gg = gl[b * 16 + j * 4 + 1];
      float gf = gl[b * 16 + j * 4 + 2];
      float go = gl[b * 16 + j * 4 + 3];
      float cold = (t == 0) ? 0.0f : cst[tid];
      float hold;
      if (isL2) hold = (t == 0) ? 0.0f : hs[b * LDHD + 512 + colg];
      else hold = (t == 0) ? 0.0f : hs[b * LDHD + colg];
      float nc = sigm(gf + 1.0f) * cold + sigm(gi) * tanhf(gg);
      float nh = sigm(go) * tanhf(nc);
      size_t mi = ((size_t)b * 512 + t) * 512 + colg;
      bool mh = mask_at(zh, mi, mmode);
      bool mc = mask_at(zc, mi, mmode);
      cst[tid] = mc ? cold : nc;
      hN[(size_t)(t * 16 + b) * 512 + colg] = nh;
      hC[(size_t)(t * 16 + b) * 512 + colg] = mh ? hold : nh;
    }
    __threadfence();
    __syncthreads();
    if (tid == 0)
      __hip_atomic_fetch_add((isL2 ? cnt2 : cnt1) + t, 1u, __ATOMIC_RELEASE, __HIP_MEMORY_SCOPE_AGENT);
  }
}

// ---------------- projection: [cond | nh1 | nh2] @ proj_w + b ----------------
__global__ __launch_bounds__(320) void k_proj(const float* __restrict__ cond,
                                              const float* __restrict__ h1n,
                                              const float* __restrict__ h2n,
                                              const float* __restrict__ pw,
                                              const float* __restrict__ pb,
                                              float* __restrict__ mel) {
  __shared__ float as_[4 * 1536];
  int r0 = blockIdx.x * 4;
  for (int i = threadIdx.x; i < 4 * 1536; i += 320) {
    int row = i / 1536, k = i % 1536;
    int r = r0 + row;
    int b = r >> 9, t = r & 511;
    float v;
    if (k < 512) v = cond[(size_t)r * 512 + k];
    else if (k < 1024) v = h1n[(size_t)(t * 16 + b) * 512 + (k - 512)];
    else v = h2n[(size_t)(t * 16 + b) * 512 + (k - 1024)];
    as_[i] = v;
  }
  __syncthreads();
  int row = threadIdx.x / 80, co = threadIdx.x % 80;
  float acc = pb[co];
  for (int k = 0; k < 1536; ++k) acc += as_[row * 1536 + k] * pw[(size_t)k * 80 + co];
  mel[(size_t)(r0 + row) * 80 + co] = acc;
}

// ---------------- k=5 conv, generic Cin->Cout, SAME ----------------
__global__ __launch_bounds__(256) void k_conv5(const float* __restrict__ X, int Cin,
                                               float* __restrict__ Y, int Cout,
                                               const float* __restrict__ Wc,
                                               const float* __restrict__ bias) {
  extern __shared__ float ys[];  // 12*Cin
  int blk = blockIdx.x;
  int b = blk >> 6, t0 = (blk & 63) * 8;
  for (int i = threadIdx.x; i < 12 * Cin; i += 256) {
    int rr = i / Cin, ci = i % Cin;
    int tt = t0 - 2 + rr;
    ys[i] = (tt >= 0 && tt < 512) ? X[(size_t)(b * 512 + tt) * Cin + ci] : 0.0f;
  }
  __syncthreads();
  for (int co = threadIdx.x; co < Cout; co += 256) {
    float acc[8];
    float bv = bias ? bias[co] : 0.0f;
#pragma unroll
    for (int j = 0; j < 8; ++j) acc[j] = bv;
    for (int dt = 0; dt < 5; ++dt)
      for (int ci = 0; ci < Cin; ++ci) {
        float wv = Wc[(size_t)(dt * Cin + ci) * Cout + co];
#pragma unroll
        for (int j = 0; j < 8; ++j) acc[j] += ys[(j + dt) * Cin + ci] * wv;
      }
#pragma unroll
    for (int j = 0; j < 8; ++j) Y[(size_t)(b * 512 + t0 + j) * Cout + co] = acc[j];
  }
}

__global__ void k_out(const float* __restrict__ mel, const float* __restrict__ res,
                      void* __restrict__ out, const int* __restrict__ flags) {
  int i = blockIdx.x * 256 + threadIdx.x;
  float m = mel[i];
  float f = m + res[i];
  if (flags[0]) {
    ((float*)out)[i] = m;
    ((float*)out)[655360 + i] = f;
  } else {
    unsigned short* o = (unsigned short*)out;
    o[i] = f2b(m);
    o[655360 + i] = f2b(f);
  }
}

// ---------------- host launch ----------------
extern "C" void kernel_launch(void* const* d_in, const int* in_sizes, int n_in,
                              void* d_out, int out_size, void* d_ws, size_t ws_size,
                              hipStream_t stream) {
  char* ws = (char*)d_ws;
  size_t o = 0;
  auto A_ = [&](size_t nb) { size_t r = o; o += (nb + 255) & ~(size_t)255; return r; };
  const size_t FLAGS = A_(256);
  const size_t SYNC = A_(8192);
  const size_t STATS = A_(4096);
  const size_t C_MELS = A_(655360ull * 4), C_DUR = A_(4096 * 4), C_EMB = A_(65536 * 4),
               C_ECW = A_(589824ull * 4), C_EBS = A_(768 * 4), C_EBO = A_(768 * 4),
               C_LFW = A_(524288ull * 4), C_LFB = A_(1024 * 4), C_LBW = A_(524288ull * 4),
               C_LBB = A_(1024 * 4), C_PW1 = A_(20480 * 4), C_P1S = A_(256 * 4),
               C_P1O = A_(256 * 4), C_PW2 = A_(65536 * 4), C_P2S = A_(256 * 4),
               C_P2O = A_(256 * 4), C_DW1 = A_(2621440ull * 4), C_DB1 = A_(2048 * 4),
               C_DW2 = A_(3670016ull * 4), C_DB2 = A_(2048 * 4), C_PRW = A_(122880ull * 4),
               C_PRB = A_(512), C_W0 = A_(204800ull * 4), C_WM = A_(3932160ull * 4),
               C_W4 = A_(204800ull * 4), C_B4 = A_(512), C_PBS = A_(2048 * 4),
               C_PBO = A_(2048 * 4);
  const size_t R1 = A_(16777216), R2 = A_(16777216), R3 = A_(16777216), R4 = A_(16777216),
               MID = A_(4096 * 4), R5 = A_(16777216), R6 = A_(16777216), R7 = A_(25165824),
               D1X = A_(33554432), D2X = A_(33554432), MELP = A_(2621440);
  const size_t XA = R1, XB = R1 + 4194304, H1C = R1;
  const size_t GF = R2, H2C = R2;
  const size_t GB = R3, H1N = R3;
  const size_t ENC = R4, H2N = R4;
  const size_t COND = R5, PA = R5;
  const size_t PREA = R6, PREB = R6 + 8388608, PB = R6;
  const size_t DECIN = R7, RESID = R7;

  auto F = [&](size_t off) { return (float*)(ws + off); };
  int* flags = (int*)(ws + FLAGS);
  unsigned int* cntE = (unsigned int*)(ws + SYNC);
  unsigned int* cnt1 = (unsigned int*)(ws + SYNC + 2048);
  unsigned int* cnt2 = (unsigned int*)(ws + SYNC + 4096);

  hipMemsetAsync(ws + SYNC, 0, 8192, stream);
  k_detect<<<1, 256, 0, stream>>>(d_in[8], d_in[4], flags);

  struct CV { int idx; size_t off; int n; };
  const CV cvs[] = {
      {2, C_MELS, 655360}, {3, C_DUR, 4096}, {8, C_EMB, 65536}, {9, C_ECW, 589824},
      {10, C_EBS, 768}, {11, C_EBO, 768}, {12, C_LFW, 524288}, {13, C_LFB, 1024},
      {14, C_LBW, 524288}, {15, C_LBB, 1024}, {16, C_PW1, 20480}, {17, C_P1S, 256},
      {18, C_P1O, 256}, {19, C_PW2, 65536}, {20, C_P2S, 256}, {21, C_P2O, 256},
      {22, C_DW1, 2621440}, {23, C_DB1, 2048}, {24, C_DW2, 3670016}, {25, C_DB2, 2048},
      {26, C_PRW, 122880}, {27, C_PRB, 80}, {28, C_W0, 204800}, {29, C_WM, 3932160},
      {30, C_W4, 204800}, {31, C_B4, 80}, {32, C_PBS, 2048}, {33, C_PBO, 2048}};
  for (int i = 0; i < (int)(sizeof(cvs) / sizeof(cvs[0])); ++i)
    k_cvt<<<(cvs[i].n + 255) / 256, 256, 0, stream>>>(d_in[cvs[i].idx], F(cvs[i].off), cvs[i].n, flags);

  k_embed<<<4096, 256, 0, stream>>>((const int*)d_in[0], F(C_EMB), F(XA));
  for (int i = 0; i < 3; ++i) {
    k_conv3<<<1024, 256, 0, stream>>>(F(XA), F(C_ECW) + (size_t)i * 196608, F(XB));
    k_colstats<<<256, 256, 0, stream>>>(F(XB), 4096, 256, F(STATS));
    k_bnact<0><<<4096, 256, 0, stream>>>(F(XB), F(XA), F(STATS), F(C_EBS) + i * 256, F(C_EBO) + i * 256, 255, 1048576);
  }
  k_gemm<0><<<dim3(256, 4), 256, 0, stream>>>(F(XA), F(C_LFW), F(C_LFB), (void*)(ws + GF), 4096, 256, 1024);
  k_gemm<0><<<dim3(256, 4), 256, 0, stream>>>(F(XA), F(C_LBW), F(C_LBB), (void*)(ws + GB), 4096, 256, 1024);
  k_cumsum<<<1, 64, 0, stream>>>(F(C_DUR), F(MID));
  k_enc_lstm<<<128, 256, 0, stream>>>(F(GF), F(GB), F(C_LFW), F(C_LBW), F(ENC), (const int*)d_in[1], cntE);
  k_upsample<<<512, 256, 0, stream>>>(F(MID), F(ENC), F(COND));

  k_gemm<0><<<dim3(512, 1), 256, 0, stream>>>(F(C_MELS), F(C_PW1), nullptr, (void*)(ws + PREA), 8192, 80, 256);
  k_colstats<<<256, 256, 0, stream>>>(F(PREA), 8192, 256, F(STATS));
  k_bnact<0><<<8192, 256, 0, stream>>>(F(PREA), F(PREB), F(STATS), F(C_P1S), F(C_P1O), 255, 2097152);
  k_gemm<0><<<dim3(512, 1), 256, 0, stream>>>(F(PREB), F(C_PW2), nullptr, (void*)(ws + PREA), 8192, 256, 256);
  k_colstats<<<256, 256, 0, stream>>>(F(PREA), 8192, 256, F(STATS));
  k_bnact<0><<<8192, 256, 0, stream>>>(F(PREA), F(PREB), F(STATS), F(C_P2S), F(C_P2O), 255, 2097152);

  k_concat<<<24576, 256, 0, stream>>>(F(COND), F(PREB), F(DECIN));
  k_gemm<1><<<dim3(512, 8), 256, 0, stream>>>(F(DECIN), F(C_DW1), F(C_DB1), (void*)(ws + D1X), 8192, 768, 2048);
  k_gemm<1><<<dim3(512, 8), 256, 0, stream>>>(F(DECIN), F(C_DW2), F(C_DB2), (void*)(ws + D2X), 8192, 768, 2048);
  k_dec_lstm<<<256, 256, 0, stream>>>((const unsigned short*)(ws + D1X), (const unsigned short*)(ws + D2X),
                                      F(C_DW1), F(C_DW2), d_in[4], d_in[5], d_in[6], d_in[7],
                                      F(H1C), F(H1N), F(H2C), F(H2N), cnt1, cnt2, flags);
  k_proj<<<2048, 320, 0, stream>>>(F(COND), F(H1N), F(H2N), F(C_PRW), F(C_PRB), F(MELP));

  k_conv5<<<1024, 256, 12 * 80 * 4, stream>>>(F(MELP), 80, F(PA), 512, F(C_W0), nullptr);
  k_colstats<<<512, 256, 0, stream>>>(F(PA), 8192, 512, F(STATS));
  k_bnact<1><<<16384, 256, 0, stream>>>(F(PA), F(PB), F(STATS), F(C_PBS), F(C_PBO), 511, 4194304);
  for (int i = 0; i < 3; ++i) {
    k_conv5<<<1024, 256, 12 * 512 * 4, stream>>>(F(PB), 512, F(PA), 512, F(C_WM) + (size_t)i * 1310720, nullptr);
    k_colstats<<<512, 256, 0, stream>>>(F(PA), 8192, 512, F(STATS));
    k_bnact<1><<<16384, 256, 0, stream>>>(F(PA), F(PB), F(STATS), F(C_PBS) + (i + 1) * 512, F(C_PBO) + (i + 1) * 512, 511, 4194304);
  }
  k_conv5<<<1024, 256, 12 * 512 * 4, stream>>>(F(PB), 512, F(RESID), 80, F(C_W4), F(C_B4));
  k_out<<<2560, 256, 0, stream>>>(F(MELP), F(RESID), d_out, flags);
}

// Round 2
// 20212.930 us; speedup vs baseline: 1.7802x; 1.7802x over previous
//
#include <hip/hip_runtime.h>

#define EPSV 1e-5f

__device__ __forceinline__ float b2f(unsigned short u) {
  unsigned int x = ((unsigned int)u) << 16;
  return __uint_as_float(x);
}
__device__ __forceinline__ unsigned short f2b(float f) {
  unsigned int x = __float_as_uint(f);
  unsigned int r = (x + 0x7FFFu + ((x >> 16) & 1u)) >> 16;
  return (unsigned short)r;
}
__device__ __forceinline__ float sigm(float x) { return 1.0f / (1.0f + expf(-x)); }

// write-through (coherence-point) state exchange: agent-scope relaxed atomics
// bypass the non-coherent per-XCD L2 in BOTH directions -> no wbl2/invl2 needed.
__device__ __forceinline__ void stg_wt(float* p, float v) {
  __hip_atomic_store((unsigned int*)p, __float_as_uint(v), __ATOMIC_RELAXED,
                     __HIP_MEMORY_SCOPE_AGENT);
}
__device__ __forceinline__ void ldg_wt2(const float* p, float& a, float& b) {
  unsigned long long v = __hip_atomic_load((const unsigned long long*)p, __ATOMIC_RELAXED,
                                           __HIP_MEMORY_SCOPE_AGENT);
  a = __uint_as_float((unsigned int)v);
  b = __uint_as_float((unsigned int)(v >> 32));
}

// ---------------- dtype detection ----------------
__global__ void k_detect(const void* __restrict__ embp, const void* __restrict__ zmp,
                         int* __restrict__ flags) {
  __shared__ int sh[4];
  int tid = threadIdx.x;
  if (tid < 4) sh[tid] = 0;
  __syncthreads();
  const unsigned short* u = (const unsigned short*)embp;
  int bad = 0;
  for (int i = tid; i < 4096; i += 256) {
    float f = fabsf(b2f(u[i]));
    if (!(f < 1e10f)) bad = 1;
  }
  if (bad) atomicAdd(&sh[3], 1);
  const unsigned char* p = (const unsigned char*)zmp;
  int codd = 0, c0 = 0, c1v = 0;
  for (int i = tid; i < 65536; i += 256) {
    unsigned char v = p[i];
    if (v) {
      if (i & 1) codd++;
      if ((i & 3) == 0) c0++;
      if (v == 1) c1v++;
    }
  }
  atomicAdd(&sh[0], codd); atomicAdd(&sh[1], c0); atomicAdd(&sh[2], c1v);
  __syncthreads();
  if (tid == 0) {
    flags[0] = sh[3] ? 1 : 0;
    int mode;
    if (sh[0] == 0) mode = 1;
    else if (sh[2] > 0) mode = 0;
    else if (sh[1] == 0) mode = 2;
    else mode = 3;
    flags[1] = mode;
  }
}

__global__ void k_cvt(const void* __restrict__ src, float* __restrict__ dst, int n,
                      const int* __restrict__ flags) {
  int i = blockIdx.x * 256 + threadIdx.x;
  if (i >= n) return;
  if (flags[0]) dst[i] = ((const float*)src)[i];
  else dst[i] = b2f(((const unsigned short*)src)[i]);
}

__device__ __forceinline__ bool mask_at(const void* p, size_t i, int mode) {
  switch (mode) {
    case 0: return ((const unsigned char*)p)[i] != 0;
    case 1: return ((const int*)p)[i] != 0;
    case 2: return ((const float*)p)[i] != 0.0f;
    default: return ((const unsigned short*)p)[i] != 0;
  }
}

// ---------------- embedding ----------------
__global__ void k_embed(const int* __restrict__ ph, const float* __restrict__ emb,
                        float* __restrict__ X) {
  int bl = blockIdx.x;
  int p = ph[bl];
  X[(size_t)bl * 256 + threadIdx.x] = emb[(size_t)p * 256 + threadIdx.x];
}

// ---------------- k=3 conv, E=256 -> E=256, SAME ----------------
__global__ __launch_bounds__(256) void k_conv3(const float* __restrict__ X,
                                               const float* __restrict__ Wc,
                                               float* __restrict__ Y) {
  __shared__ float xs[6 * 256];
  int blk = blockIdx.x;
  int b = blk >> 6, l0 = (blk & 63) * 4;
  for (int i = threadIdx.x; i < 6 * 256; i += 256) {
    int dl = i >> 8, ci = i & 255;
    int ll = l0 - 1 + dl;
    xs[i] = (ll >= 0 && ll < 256) ? X[(size_t)(b * 256 + ll) * 256 + ci] : 0.0f;
  }
  __syncthreads();
  int co = threadIdx.x;
  float acc[4] = {0.f, 0.f, 0.f, 0.f};
  for (int i = 0; i < 768; ++i) {
    int d = i >> 8, ci = i & 255;
    float wv = Wc[(size_t)i * 256 + co];
#pragma unroll
    for (int j = 0; j < 4; ++j) acc[j] += xs[(d + j) * 256 + ci] * wv;
  }
#pragma unroll
  for (int j = 0; j < 4; ++j) Y[(size_t)(b * 256 + l0 + j) * 256 + co] = acc[j];
}

// ---------------- per-channel mean/var ----------------
__global__ __launch_bounds__(256) void k_colstats(const float* __restrict__ X, int R, int C,
                                                  float* __restrict__ st) {
  int c = blockIdx.x;
  float s = 0.f, q = 0.f;
  for (int r = threadIdx.x; r < R; r += 256) {
    float v = X[(size_t)r * C + c];
    s += v; q += v * v;
  }
  __shared__ float rs_[256], rq_[256];
  rs_[threadIdx.x] = s; rq_[threadIdx.x] = q;
  __syncthreads();
  for (int k = 128; k > 0; k >>= 1) {
    if (threadIdx.x < k) { rs_[threadIdx.x] += rs_[threadIdx.x + k]; rq_[threadIdx.x] += rq_[threadIdx.x + k]; }
    __syncthreads();
  }
  if (threadIdx.x == 0) {
    float m = rs_[0] / R;
    st[c] = m;
    st[C + c] = rq_[0] / R - m * m;
  }
}

template <int ACT>
__global__ void k_bnact(const float* __restrict__ X, float* __restrict__ Y,
                        const float* __restrict__ st, const float* __restrict__ sc,
                        const float* __restrict__ of, int Cmask, int n) {
  int i = blockIdx.x * 256 + threadIdx.x;
  if (i >= n) return;
  int C = Cmask + 1;
  int c = i & Cmask;
  float m = st[c], v = st[C + c];
  float y = (X[i] - m) * rsqrtf(v + EPSV) * sc[c] + of[c];
  Y[i] = ACT ? tanhf(y) : fmaxf(y, 0.0f);
}

// ---------------- generic GEMM ----------------
// OBF: 0=f32 row-major, 1=bf16 row-major,
//      2=bf16 decoder-gate layout [t][w128][b16][g4*4+j],
//      3=f32  encoder-gate layout [l][w64][b16][g4*4+j]
template <int OBF>
__global__ __launch_bounds__(256) void k_gemm(const float* __restrict__ Ap,
                                              const float* __restrict__ Bp,
                                              const float* __restrict__ bias,
                                              void* __restrict__ Cp, int M, int K, int N) {
  __shared__ float al[16 * 768];
  int row0 = blockIdx.x * 16;
  int c = blockIdx.y * 256 + threadIdx.x;
  for (int i = threadIdx.x; i < 16 * K; i += 256) al[i] = Ap[(size_t)row0 * K + i];
  __syncthreads();
  float acc[16];
  float bv = bias ? bias[c] : 0.0f;
#pragma unroll
  for (int j = 0; j < 16; ++j) acc[j] = bv;
  for (int k = 0; k < K; ++k) {
    float b = Bp[(size_t)k * N + c];
#pragma unroll
    for (int j = 0; j < 16; ++j) acc[j] += al[j * K + k] * b;
  }
  if (OBF == 0) {
    float* C = (float*)Cp;
#pragma unroll
    for (int j = 0; j < 16; ++j) C[(size_t)(row0 + j) * N + c] = acc[j];
  } else if (OBF == 1) {
    unsigned short* C = (unsigned short*)Cp;
#pragma unroll
    for (int j = 0; j < 16; ++j) C[(size_t)(row0 + j) * N + c] = f2b(acc[j]);
  } else if (OBF == 2) {
    unsigned short* C = (unsigned short*)Cp;
    int g = c >> 9, w = (c & 511) >> 2, jj = c & 3;
#pragma unroll
    for (int j = 0; j < 16; ++j) {
      int row = row0 + j;
      int b = row >> 9, t = row & 511;
      C[((size_t)t * 128 + w) * 256 + b * 16 + g * 4 + jj] = f2b(acc[j]);
    }
  } else {
    float* C = (float*)Cp;
    int g = c >> 8, w = (c & 255) >> 2, jj = c & 3;
#pragma unroll
    for (int j = 0; j < 16; ++j) {
      int row = row0 + j;
      int b = row >> 8, l = row & 255;
      C[((size_t)l * 64 + w) * 256 + b * 16 + g * 4 + jj] = acc[j];
    }
  }
}

// ---------------- duration cumsum ----------------
__global__ void k_cumsum(const float* __restrict__ dur, float* __restrict__ mid) {
  int b = threadIdx.x;
  if (b >= 16) return;
  float run = 0.f;
  for (int l = 0; l < 256; ++l) {
    float d = dur[b * 256 + l];
    run += d;
    mid[b * 256 + l] = run - 0.5f * d;
  }
}

// ---------------- persistent bi-LSTM encoder ----------------
__global__ __launch_bounds__(256) void k_enc_lstm(const float* __restrict__ GFp,
                                                  const float* __restrict__ GBp,
                                                  const float* __restrict__ Wf,
                                                  const float* __restrict__ Wb,
                                                  float* __restrict__ enc,
                                                  const int* __restrict__ lengths,
                                                  unsigned int* __restrict__ cnt) {
  const int tid = threadIdx.x;
  const int wg = blockIdx.x;
  const int dir = wg >> 6;
  const int w = wg & 63;
  const float* Gpre = dir ? GBp : GFp;
  const float* W = dir ? Wb : Wf;
  unsigned int* c_self = cnt + dir * 256;

  __shared__ float hs[16 * 264];
  __shared__ float wh[16 * 264];
  __shared__ float part[16 * 257];
  __shared__ float gl[256];
  __shared__ float cst[64];
  __shared__ int rs[16];

  for (int i = tid; i < 16 * 256; i += 256) {
    int gc = i >> 8, k = i & 255;
    int g = gc >> 2, j = gc & 3;
    wh[gc * 264 + k] = W[(size_t)(256 + k) * 1024 + g * 256 + (w * 4 + j)];
  }
  if (tid < 64) cst[tid] = 0.0f;
  __syncthreads();

  const int og = tid >> 4, s = tid & 15;
  const int bq = og >> 2, jj = og & 3;

  for (int t = 0; t < 256; ++t) {
    const int l = dir ? (255 - t) : t;
    if (tid < 16) rs[tid] = (dir == 1) && (l >= lengths[tid] - 1);
    if (t > 0 && tid == 0) {
      unsigned int gcount = 0;
      while (__hip_atomic_load(c_self + (t - 1), __ATOMIC_RELAXED, __HIP_MEMORY_SCOPE_AGENT) < 64u) {
        __builtin_amdgcn_s_sleep(8);
        if (++gcount > (1u << 16)) break;
      }
    }
    __syncthreads();
    if (t > 0) {
      const int lprev = dir ? (l + 1) : (l - 1);
      for (int i = tid; i < 16 * 128; i += 256) {
        int b = i >> 7, k2 = i & 127;
        float a0, a1;
        ldg_wt2(&enc[(size_t)(b * 256 + lprev) * 512 + dir * 256 + 2 * k2], a0, a1);
        if (rs[b]) { a0 = 0.0f; a1 = 0.0f; }
        hs[b * 264 + 2 * k2] = a0;
        hs[b * 264 + 2 * k2 + 1] = a1;
      }
    }
    __syncthreads();

    float acc[4][4];
#pragma unroll
    for (int a = 0; a < 4; ++a) { acc[a][0] = 0; acc[a][1] = 0; acc[a][2] = 0; acc[a][3] = 0; }
    if (t > 0) {
      const int b0 = bq * 4;
#pragma unroll 4
      for (int i = 0; i < 16; ++i) {
        int k = i * 16 + s;
        float h0 = hs[(b0 + 0) * 264 + k];
        float h1 = hs[(b0 + 1) * 264 + k];
        float h2 = hs[(b0 + 2) * 264 + k];
        float h3 = hs[(b0 + 3) * 264 + k];
#pragma unroll
        for (int g = 0; g < 4; ++g) {
          float wv = wh[(g * 4 + jj) * 264 + k];
          acc[0][g] += h0 * wv; acc[1][g] += h1 * wv;
          acc[2][g] += h2 * wv; acc[3][g] += h3 * wv;
        }
      }
    }
#pragma unroll
    for (int a = 0; a < 4; ++a)
#pragma unroll
      for (int g = 0; g < 4; ++g)
        part[s * 257 + ((bq * 4 + a) * 16 + jj * 4 + g)] = acc[a][g];
    __syncthreads();
    {
      int b = tid >> 4, j = (tid >> 2) & 3, g = tid & 3;
      float sum = 0.0f;
      if (t > 0) {
#pragma unroll
        for (int ss = 0; ss < 16; ++ss) sum += part[ss * 257 + tid];
      }
      sum += Gpre[((size_t)l * 64 + w) * 256 + b * 16 + g * 4 + j];
      gl[tid] = sum;
    }
    __syncthreads();
    if (tid < 64) {
      int b = tid >> 2, j = tid & 3;
      float gi = gl[b * 16 + j * 4 + 0];
      float gg = gl[b * 16 + j * 4 + 1];
      float gf = gl[b * 16 + j * 4 + 2];
      float go = gl[b * 16 + j * 4 + 3];
      float c = cst[tid];
      if (t == 0 || rs[b]) c = 0.0f;
      c = sigm(gf + 1.0f) * c + sigm(gi) * tanhf(gg);
      float h = sigm(go) * tanhf(c);
      cst[tid] = c;
      stg_wt(&enc[(size_t)(b * 256 + l) * 512 + dir * 256 + (w * 4 + j)], h);
    }
    __syncthreads();  // drains vmcnt(0) for all waves before publish
    if (tid == 0)
      __hip_atomic_fetch_add(c_self + t, 1u, __ATOMIC_RELAXED, __HIP_MEMORY_SCOPE_AGENT);
  }
}

// ---------------- Gaussian-softmax upsampling ----------------
__global__ __launch_bounds__(256) void k_upsample(const float* __restrict__ mid,
                                                  const float* __restrict__ enc,
                                                  float* __restrict__ cond) {
  int blk = blockIdx.x;
  int b = blk >> 5, t0 = (blk & 31) * 16;
  int tid = threadIdx.x;
  __shared__ float wls[16][256];
  __shared__ float red[256];
  float mp = mid[b * 256 + tid];
  for (int tt = 0; tt < 16; ++tt) {
    float tpos = (float)(t0 + tt);
    float d = mp - tpos;
    float d2 = d * d * 0.1f;
    red[tid] = d2; __syncthreads();
    for (int k = 128; k > 0; k >>= 1) { if (tid < k) red[tid] = fminf(red[tid], red[tid + k]); __syncthreads(); }
    float mn = red[0]; __syncthreads();
    float e = expf(mn - d2);
    red[tid] = e; __syncthreads();
    for (int k = 128; k > 0; k >>= 1) { if (tid < k) red[tid] += red[tid + k]; __syncthreads(); }
    float sum = red[0]; __syncthreads();
    wls[tt][tid] = e / sum;
  }
  __syncthreads();
  float a0[16], a1[16];
#pragma unroll
  for (int i = 0; i < 16; ++i) { a0[i] = 0; a1[i] = 0; }
  for (int l = 0; l < 256; ++l) {
    float e0 = enc[(size_t)(b * 256 + l) * 512 + tid];
    float e1 = enc[(size_t)(b * 256 + l) * 512 + 256 + tid];
#pragma unroll
    for (int tt = 0; tt < 16; ++tt) { float wv = wls[tt][l]; a0[tt] += wv * e0; a1[tt] += wv * e1; }
  }
  for (int tt = 0; tt < 16; ++tt) {
    cond[(size_t)(b * 512 + t0 + tt) * 512 + tid] = a0[tt];
    cond[(size_t)(b * 512 + t0 + tt) * 512 + 256 + tid] = a1[tt];
  }
}

__global__ void k_concat(const float* __restrict__ cond, const float* __restrict__ p,
                         float* __restrict__ din) {
  size_t i = (size_t)blockIdx.x * 256 + threadIdx.x;
  int r = (int)(i / 768);
  int c = (int)(i % 768);
  din[i] = (c < 512) ? cond[(size_t)r * 512 + c] : p[(size_t)r * 256 + (c - 512)];
}

// ---------------- persistent 2-layer zoneout LSTM decoder ----------------
#define LDHD 1032
__global__ __launch_bounds__(256) void k_dec_lstm(
    const unsigned short* __restrict__ D1x, const unsigned short* __restrict__ D2x,
    const float* __restrict__ W1, const float* __restrict__ W2,
    const void* __restrict__ zh1, const void* __restrict__ zc1,
    const void* __restrict__ zh2, const void* __restrict__ zc2,
    float* __restrict__ h1c, float* __restrict__ h1n,
    float* __restrict__ h2c, float* __restrict__ h2n,
    unsigned int* __restrict__ cnt1, unsigned int* __restrict__ cnt2,
    const int* __restrict__ flags) {
  const int tid = threadIdx.x;
  const int wg = blockIdx.x;
  const bool isL2 = wg >= 128;
  const int w = isL2 ? (wg - 128) : wg;

  __shared__ float hs[16 * LDHD];
  __shared__ float wh[16 * LDHD];
  __shared__ float part[16 * 257];
  __shared__ float gl[256];
  __shared__ float cst[64];

  const int mmode = flags[1];
  const int KK = isL2 ? 1024 : 512;
  const float* W = isL2 ? W2 : W1;

  for (int i = tid; i < 16 * KK; i += 256) {
    int gc = i / KK, k = i - gc * KK;
    int g = gc >> 2, j = gc & 3;
    wh[gc * LDHD + k] = W[(size_t)(768 + k) * 2048 + g * 512 + (w * 4 + j)];
  }
  if (tid < 64) cst[tid] = 0.0f;
  __syncthreads();

  const int og = tid >> 4, s = tid & 15;
  const int bq = og >> 2, jj = og & 3;
  const int SEGI = KK >> 4;

  const void* zh = isL2 ? zh2 : zh1;
  const void* zc = isL2 ? zc2 : zc1;
  const unsigned short* Dx = isL2 ? D2x : D1x;
  float* hN = isL2 ? h2n : h1n;
  float* hC = isL2 ? h2c : h1c;

  for (int t = 0; t < 512; ++t) {
    if (tid == 0) {
      unsigned int gcount = 0;
      if (isL2) {
        while (__hip_atomic_load(cnt1 + t, __ATOMIC_RELAXED, __HIP_MEMORY_SCOPE_AGENT) < 128u) {
          __builtin_amdgcn_s_sleep(8);
          if (++gcount > (1u << 16)) break;
        }
        if (t > 0) {
          gcount = 0;
          while (__hip_atomic_load(cnt2 + (t - 1), __ATOMIC_RELAXED, __HIP_MEMORY_SCOPE_AGENT) < 128u) {
            __builtin_amdgcn_s_sleep(8);
            if (++gcount > (1u << 16)) break;
          }
        }
      } else if (t > 0) {
        while (__hip_atomic_load(cnt1 + (t - 1), __ATOMIC_RELAXED, __HIP_MEMORY_SCOPE_AGENT) < 128u) {
          __builtin_amdgcn_s_sleep(8);
          if (++gcount > (1u << 16)) break;
        }
      }
    }
    __syncthreads();
    if (isL2) {
      for (int i = tid; i < 16 * 256; i += 256) {
        int b = i >> 8, k2 = i & 255;
        float a0, a1;
        ldg_wt2(&h1n[(size_t)(t * 16 + b) * 512 + 2 * k2], a0, a1);
        hs[b * LDHD + 2 * k2] = a0;
        hs[b * LDHD + 2 * k2 + 1] = a1;
      }
      if (t > 0) {
        for (int i = tid; i < 16 * 256; i += 256) {
          int b = i >> 8, k2 = i & 255;
          float a0, a1;
          ldg_wt2(&h2c[(size_t)((t - 1) * 16 + b) * 512 + 2 * k2], a0, a1);
          hs[b * LDHD + 512 + 2 * k2] = a0;
          hs[b * LDHD + 512 + 2 * k2 + 1] = a1;
        }
      } else {
        for (int i = tid; i < 16 * 512; i += 256) {
          int b = i >> 9, k = i & 511;
          hs[b * LDHD + 512 + k] = 0.0f;
        }
      }
    } else if (t > 0) {
      for (int i = tid; i < 16 * 256; i += 256) {
        int b = i >> 8, k2 = i & 255;
        float a0, a1;
        ldg_wt2(&h1c[(size_t)((t - 1) * 16 + b) * 512 + 2 * k2], a0, a1);
        hs[b * LDHD + 2 * k2] = a0;
        hs[b * LDHD + 2 * k2 + 1] = a1;
      }
    }
    __syncthreads();

    float acc[4][4];
#pragma unroll
    for (int a = 0; a < 4; ++a) { acc[a][0] = 0; acc[a][1] = 0; acc[a][2] = 0; acc[a][3] = 0; }
    const bool doDot = isL2 || (t > 0);
    if (doDot) {
      const int b0 = bq * 4;
      for (int i = 0; i < SEGI; ++i) {
        int k = i * 16 + s;
        float h0 = hs[(b0 + 0) * LDHD + k];
        float h1v = hs[(b0 + 1) * LDHD + k];
        float h2v = hs[(b0 + 2) * LDHD + k];
        float h3v = hs[(b0 + 3) * LDHD + k];
#pragma unroll
        for (int g = 0; g < 4; ++g) {
          float wv = wh[(g * 4 + jj) * LDHD + k];
          acc[0][g] += h0 * wv; acc[1][g] += h1v * wv;
          acc[2][g] += h2v * wv; acc[3][g] += h3v * wv;
        }
      }
    }
#pragma unroll
    for (int a = 0; a < 4; ++a)
#pragma unroll
      for (int g = 0; g < 4; ++g)
        part[s * 257 + ((bq * 4 + a) * 16 + jj * 4 + g)] = acc[a][g];
    __syncthreads();
    {
      int b = tid >> 4, j = (tid >> 2) & 3, g = tid & 3;
      float sum = 0.0f;
      if (doDot) {
#pragma unroll
        for (int ss = 0; ss < 16; ++ss) sum += part[ss * 257 + tid];
      }
      sum += b2f(Dx[((size_t)t * 128 + w) * 256 + b * 16 + g * 4 + j]);
      gl[tid] = sum;
    }
    __syncthreads();
    if (tid < 64) {
      int b = tid >> 2, j = tid & 3;
      int colg = w * 4 + j;
      float gi = gl[b * 16 + j * 4 + 0];
      float gg = gl[b * 16 + j * 4 + 1];
      float gf = gl[b * 16 + j * 4 + 2];
      float go = gl[b * 16 + j * 4 + 3];
      float cold = (t == 0) ? 0.0f : cst[tid];
      float hold;
      if (isL2) hold = (t == 0) ? 0.0f : hs[b * LDHD + 512 + colg];
      else hold = (t == 0) ? 0.0f : hs[b * LDHD + colg];
      float nc = sigm(gf + 1.0f) * cold + sigm(gi) * tanhf(gg);
      float nh = sigm(go) * tanhf(nc);
      size_t mi = ((size_t)b * 512 + t) * 512 + colg;
      bool mh = mask_at(zh, mi, mmode);
      bool mc = mask_at(zc, mi, mmode);
      cst[tid] = mc ? cold : nc;
      stg_wt(&hN[(size_t)(t * 16 + b) * 512 + colg], nh);
      stg_wt(&hC[(size_t)(t * 16 + b) * 512 + colg], mh ? hold : nh);
    }
    __syncthreads();  // drains vmcnt(0) for all waves before publish
    if (tid == 0)
      __hip_atomic_fetch_add((isL2 ? cnt2 : cnt1) + t, 1u, __ATOMIC_RELAXED, __HIP_MEMORY_SCOPE_AGENT);
  }
}

// ---------------- projection ----------------
__global__ __launch_bounds__(320) void k_proj(const float* __restrict__ cond,
                                              const float* __restrict__ h1n,
                                              const float* __restrict__ h2n,
                                              const float* __restrict__ pw,
                                              const float* __restrict__ pb,
                                              float* __restrict__ mel) {
  __shared__ float as_[4 * 1536];
  int r0 = blockIdx.x * 4;
  for (int i = threadIdx.x; i < 4 * 1536; i += 320) {
    int row = i / 1536, k = i % 1536;
    int r = r0 + row;
    int b = r >> 9, t = r & 511;
    float v;
    if (k < 512) v = cond[(size_t)r * 512 + k];
    else if (k < 1024) v = h1n[(size_t)(t * 16 + b) * 512 + (k - 512)];
    else v = h2n[(size_t)(t * 16 + b) * 512 + (k - 1024)];
    as_[i] = v;
  }
  __syncthreads();
  int row = threadIdx.x / 80, co = threadIdx.x % 80;
  float acc = pb[co];
  for (int k = 0; k < 1536; ++k) acc += as_[row * 1536 + k] * pw[(size_t)k * 80 + co];
  mel[(size_t)(r0 + row) * 80 + co] = acc;
}

// ---------------- k=5 conv ----------------
__global__ __launch_bounds__(256) void k_conv5(const float* __restrict__ X, int Cin,
                                               float* __restrict__ Y, int Cout,
                                               const float* __restrict__ Wc,
                                               const float* __restrict__ bias) {
  extern __shared__ float ys[];
  int blk = blockIdx.x;
  int b = blk >> 6, t0 = (blk & 63) * 8;
  for (int i = threadIdx.x; i < 12 * Cin; i += 256) {
    int rr = i / Cin, ci = i % Cin;
    int tt = t0 - 2 + rr;
    ys[i] = (tt >= 0 && tt < 512) ? X[(size_t)(b * 512 + tt) * Cin + ci] : 0.0f;
  }
  __syncthreads();
  for (int co = threadIdx.x; co < Cout; co += 256) {
    float acc[8];
    float bv = bias ? bias[co] : 0.0f;
#pragma unroll
    for (int j = 0; j < 8; ++j) acc[j] = bv;
    for (int dt = 0; dt < 5; ++dt)
      for (int ci = 0; ci < Cin; ++ci) {
        float wv = Wc[(size_t)(dt * Cin + ci) * Cout + co];
#pragma unroll
        for (int j = 0; j < 8; ++j) acc[j] += ys[(j + dt) * Cin + ci] * wv;
      }
#pragma unroll
    for (int j = 0; j < 8; ++j) Y[(size_t)(b * 512 + t0 + j) * Cout + co] = acc[j];
  }
}

__global__ void k_out(const float* __restrict__ mel, const float* __restrict__ res,
                      void* __restrict__ out, const int* __restrict__ flags) {
  int i = blockIdx.x * 256 + threadIdx.x;
  float m = mel[i];
  float f = m + res[i];
  if (flags[0]) {
    ((float*)out)[i] = m;
    ((float*)out)[655360 + i] = f;
  } else {
    unsigned short* o = (unsigned short*)out;
    o[i] = f2b(m);
    o[655360 + i] = f2b(f);
  }
}

// ---------------- host launch ----------------
extern "C" void kernel_launch(void* const* d_in, const int* in_sizes, int n_in,
                              void* d_out, int out_size, void* d_ws, size_t ws_size,
                              hipStream_t stream) {
  char* ws = (char*)d_ws;
  size_t o = 0;
  auto A_ = [&](size_t nb) { size_t r = o; o += (nb + 255) & ~(size_t)255; return r; };
  const size_t FLAGS = A_(256);
  const size_t SYNC = A_(8192);
  const size_t STATS = A_(4096);
  const size_t C_MELS = A_(655360ull * 4), C_DUR = A_(4096 * 4), C_EMB = A_(65536 * 4),
               C_ECW = A_(589824ull * 4), C_EBS = A_(768 * 4), C_EBO = A_(768 * 4),
               C_LFW = A_(524288ull * 4), C_LFB = A_(1024 * 4), C_LBW = A_(524288ull * 4),
               C_LBB = A_(1024 * 4), C_PW1 = A_(20480 * 4), C_P1S = A_(256 * 4),
               C_P1O = A_(256 * 4), C_PW2 = A_(65536 * 4), C_P2S = A_(256 * 4),
               C_P2O = A_(256 * 4), C_DW1 = A_(2621440ull * 4), C_DB1 = A_(2048 * 4),
               C_DW2 = A_(3670016ull * 4), C_DB2 = A_(2048 * 4), C_PRW = A_(122880ull * 4),
               C_PRB = A_(512), C_W0 = A_(204800ull * 4), C_WM = A_(3932160ull * 4),
               C_W4 = A_(204800ull * 4), C_B4 = A_(512), C_PBS = A_(2048 * 4),
               C_PBO = A_(2048 * 4);
  const size_t R1 = A_(16777216), R2 = A_(16777216), R3 = A_(16777216), R4 = A_(16777216),
               MID = A_(4096 * 4), R5 = A_(16777216), R6 = A_(16777216), R7 = A_(25165824),
               D1X = A_(33554432), D2X = A_(33554432), MELP = A_(2621440);
  const size_t XA = R1, XB = R1 + 4194304, H1C = R1;
  const size_t GF = R2, H2C = R2;
  const size_t GB = R3, H1N = R3;
  const size_t ENC = R4, H2N = R4;
  const size_t COND = R5, PA = R5;
  const size_t PREA = R6, PREB = R6 + 8388608, PB = R6;
  const size_t DECIN = R7, RESID = R7;

  auto F = [&](size_t off) { return (float*)(ws + off); };
  int* flags = (int*)(ws + FLAGS);
  unsigned int* cntE = (unsigned int*)(ws + SYNC);
  unsigned int* cnt1 = (unsigned int*)(ws + SYNC + 2048);
  unsigned int* cnt2 = (unsigned int*)(ws + SYNC + 4096);

  hipMemsetAsync(ws + SYNC, 0, 8192, stream);
  k_detect<<<1, 256, 0, stream>>>(d_in[8], d_in[4], flags);

  struct CV { int idx; size_t off; int n; };
  const CV cvs[] = {
      {2, C_MELS, 655360}, {3, C_DUR, 4096}, {8, C_EMB, 65536}, {9, C_ECW, 589824},
      {10, C_EBS, 768}, {11, C_EBO, 768}, {12, C_LFW, 524288}, {13, C_LFB, 1024},
      {14, C_LBW, 524288}, {15, C_LBB, 1024}, {16, C_PW1, 20480}, {17, C_P1S, 256},
      {18, C_P1O, 256}, {19, C_PW2, 65536}, {20, C_P2S, 256}, {21, C_P2O, 256},
      {22, C_DW1, 2621440}, {23, C_DB1, 2048}, {24, C_DW2, 3670016}, {25, C_DB2, 2048},
      {26, C_PRW, 122880}, {27, C_PRB, 80}, {28, C_W0, 204800}, {29, C_WM, 3932160},
      {30, C_W4, 204800}, {31, C_B4, 80}, {32, C_PBS, 2048}, {33, C_PBO, 2048}};
  for (int i = 0; i < (int)(sizeof(cvs) / sizeof(cvs[0])); ++i)
    k_cvt<<<(cvs[i].n + 255) / 256, 256, 0, stream>>>(d_in[cvs[i].idx], F(cvs[i].off), cvs[i].n, flags);

  k_embed<<<4096, 256, 0, stream>>>((const int*)d_in[0], F(C_EMB), F(XA));
  for (int i = 0; i < 3; ++i) {
    k_conv3<<<1024, 256, 0, stream>>>(F(XA), F(C_ECW) + (size_t)i * 196608, F(XB));
    k_colstats<<<256, 256, 0, stream>>>(F(XB), 4096, 256, F(STATS));
    k_bnact<0><<<4096, 256, 0, stream>>>(F(XB), F(XA), F(STATS), F(C_EBS) + i * 256, F(C_EBO) + i * 256, 255, 1048576);
  }
  k_gemm<3><<<dim3(256, 4), 256, 0, stream>>>(F(XA), F(C_LFW), F(C_LFB), (void*)(ws + GF), 4096, 256, 1024);
  k_gemm<3><<<dim3(256, 4), 256, 0, stream>>>(F(XA), F(C_LBW), F(C_LBB), (void*)(ws + GB), 4096, 256, 1024);
  k_cumsum<<<1, 64, 0, stream>>>(F(C_DUR), F(MID));
  k_enc_lstm<<<128, 256, 0, stream>>>(F(GF), F(GB), F(C_LFW), F(C_LBW), F(ENC), (const int*)d_in[1], cntE);
  k_upsample<<<512, 256, 0, stream>>>(F(MID), F(ENC), F(COND));

  k_gemm<0><<<dim3(512, 1), 256, 0, stream>>>(F(C_MELS), F(C_PW1), nullptr, (void*)(ws + PREA), 8192, 80, 256);
  k_colstats<<<256, 256, 0, stream>>>(F(PREA), 8192, 256, F(STATS));
  k_bnact<0><<<8192, 256, 0, stream>>>(F(PREA), F(PREB), F(STATS), F(C_P1S), F(C_P1O), 255, 2097152);
  k_gemm<0><<<dim3(512, 1), 256, 0, stream>>>(F(PREB), F(C_PW2), nullptr, (void*)(ws + PREA), 8192, 256, 256);
  k_colstats<<<256, 256, 0, stream>>>(F(PREA), 8192, 256, F(STATS));
  k_bnact<0><<<8192, 256, 0, stream>>>(F(PREA), F(PREB), F(STATS), F(C_P2S), F(C_P2O), 255, 2097152);

  k_concat<<<24576, 256, 0, stream>>>(F(COND), F(PREB), F(DECIN));
  k_gemm<2><<<dim3(512, 8), 256, 0, stream>>>(F(DECIN), F(C_DW1), F(C_DB1), (void*)(ws + D1X), 8192, 768, 2048);
  k_gemm<2><<<dim3(512, 8), 256, 0, stream>>>(F(DECIN), F(C_DW2), F(C_DB2), (void*)(ws + D2X), 8192, 768, 2048);
  k_dec_lstm<<<256, 256, 0, stream>>>((const unsigned short*)(ws + D1X), (const unsigned short*)(ws + D2X),
                                      F(C_DW1), F(C_DW2), d_in[4], d_in[5], d_in[6], d_in[7],
                                      F(H1C), F(H1N), F(H2C), F(H2N), cnt1, cnt2, flags);
  k_proj<<<2048, 320, 0, stream>>>(F(COND), F(H1N), F(H2N), F(C_PRW), F(C_PRB), F(MELP));

  k_conv5<<<1024, 256, 12 * 80 * 4, stream>>>(F(MELP), 80, F(PA), 512, F(C_W0), nullptr);
  k_colstats<<<512, 256, 0, stream>>>(F(PA), 8192, 512, F(STATS));
  k_bnact<1><<<16384, 256, 0, stream>>>(F(PA), F(PB), F(STATS), F(C_PBS), F(C_PBO), 511, 4194304);
  for (int i = 0; i < 3; ++i) {
    k_conv5<<<1024, 256, 12 * 512 * 4, stream>>>(F(PB), 512, F(PA), 512, F(C_WM) + (size_t)i * 1310720, nullptr);
    k_colstats<<<512, 256, 0, stream>>>(F(PA), 8192, 512, F(STATS));
    k_bnact<1><<<16384, 256, 0, stream>>>(F(PA), F(PB), F(STATS), F(C_PBS) + (i + 1) * 512, F(C_PBO) + (i + 1) * 512, 511, 4194304);
  }
  k_conv5<<<1024, 256, 12 * 512 * 4, stream>>>(F(PB), 512, F(RESID), 80, F(C_W4), F(C_B4));
  k_out<<<2560, 256, 0, stream>>>(F(MELP), F(RESID), d_out, flags);
}

// Round 4
// 19675.246 us; speedup vs baseline: 1.8288x; 1.0273x over previous
//
#include <hip/hip_runtime.h>

#define EPSV 1e-5f

__device__ __forceinline__ float b2f(unsigned short u) {
  unsigned int x = ((unsigned int)u) << 16;
  return __uint_as_float(x);
}
__device__ __forceinline__ unsigned short f2b(float f) {
  unsigned int x = __float_as_uint(f);
  unsigned int r = (x + 0x7FFFu + ((x >> 16) & 1u)) >> 16;
  return (unsigned short)r;
}
__device__ __forceinline__ float sigm(float x) { return 1.0f / (1.0f + expf(-x)); }

// write-through publish: agent-scope relaxed atomic store (bypasses non-coherent L2)
__device__ __forceinline__ void stg_wt(float* p, float v) {
  __hip_atomic_store((unsigned int*)p, __float_as_uint(v), __ATOMIC_RELAXED,
                     __HIP_MEMORY_SCOPE_AGENT);
}
// agent-scope 8B state load (bypasses L1/L2 -> always coherence-point fresh)
__device__ __forceinline__ void ldg_wt2(const float* p, float& a, float& b) {
  unsigned long long v = __hip_atomic_load((const unsigned long long*)p, __ATOMIC_RELAXED,
                                           __HIP_MEMORY_SCOPE_AGENT);
  a = __uint_as_float((unsigned int)v);
  b = __uint_as_float((unsigned int)(v >> 32));
}
__device__ __forceinline__ unsigned int ldcnt(const unsigned int* p) {
  return __hip_atomic_load(p, __ATOMIC_RELAXED, __HIP_MEMORY_SCOPE_AGENT);
}

// ---------------- dtype detection ----------------
__global__ void k_detect(const void* __restrict__ embp, const void* __restrict__ zmp,
                         int* __restrict__ flags) {
  __shared__ int sh[4];
  int tid = threadIdx.x;
  if (tid < 4) sh[tid] = 0;
  __syncthreads();
  const unsigned short* u = (const unsigned short*)embp;
  int bad = 0;
  for (int i = tid; i < 4096; i += 256) {
    float f = fabsf(b2f(u[i]));
    if (!(f < 1e10f)) bad = 1;
  }
  if (bad) atomicAdd(&sh[3], 1);
  const unsigned char* p = (const unsigned char*)zmp;
  int codd = 0, c0 = 0, c1v = 0;
  for (int i = tid; i < 65536; i += 256) {
    unsigned char v = p[i];
    if (v) {
      if (i & 1) codd++;
      if ((i & 3) == 0) c0++;
      if (v == 1) c1v++;
    }
  }
  atomicAdd(&sh[0], codd); atomicAdd(&sh[1], c0); atomicAdd(&sh[2], c1v);
  __syncthreads();
  if (tid == 0) {
    flags[0] = sh[3] ? 1 : 0;
    int mode;
    if (sh[0] == 0) mode = 1;
    else if (sh[2] > 0) mode = 0;
    else if (sh[1] == 0) mode = 2;
    else mode = 3;
    flags[1] = mode;
  }
}

__global__ void k_cvt(const void* __restrict__ src, float* __restrict__ dst, int n,
                      const int* __restrict__ flags) {
  int i = blockIdx.x * 256 + threadIdx.x;
  if (i >= n) return;
  if (flags[0]) dst[i] = ((const float*)src)[i];
  else dst[i] = b2f(((const unsigned short*)src)[i]);
}

__device__ __forceinline__ bool mask_at(const void* p, size_t i, int mode) {
  switch (mode) {
    case 0: return ((const unsigned char*)p)[i] != 0;
    case 1: return ((const int*)p)[i] != 0;
    case 2: return ((const float*)p)[i] != 0.0f;
    default: return ((const unsigned short*)p)[i] != 0;
  }
}

// ---------------- embedding ----------------
__global__ void k_embed(const int* __restrict__ ph, const float* __restrict__ emb,
                        float* __restrict__ X) {
  int bl = blockIdx.x;
  int p = ph[bl];
  X[(size_t)bl * 256 + threadIdx.x] = emb[(size_t)p * 256 + threadIdx.x];
}

// ---------------- k=3 conv, E=256 -> E=256, SAME ----------------
__global__ __launch_bounds__(256) void k_conv3(const float* __restrict__ X,
                                               const float* __restrict__ Wc,
                                               float* __restrict__ Y) {
  __shared__ float xs[6 * 256];
  int blk = blockIdx.x;
  int b = blk >> 6, l0 = (blk & 63) * 4;
  for (int i = threadIdx.x; i < 6 * 256; i += 256) {
    int dl = i >> 8, ci = i & 255;
    int ll = l0 - 1 + dl;
    xs[i] = (ll >= 0 && ll < 256) ? X[(size_t)(b * 256 + ll) * 256 + ci] : 0.0f;
  }
  __syncthreads();
  int co = threadIdx.x;
  float acc[4] = {0.f, 0.f, 0.f, 0.f};
  for (int i = 0; i < 768; ++i) {
    int d = i >> 8, ci = i & 255;
    float wv = Wc[(size_t)i * 256 + co];
#pragma unroll
    for (int j = 0; j < 4; ++j) acc[j] += xs[(d + j) * 256 + ci] * wv;
  }
#pragma unroll
  for (int j = 0; j < 4; ++j) Y[(size_t)(b * 256 + l0 + j) * 256 + co] = acc[j];
}

// ---------------- per-channel mean/var ----------------
__global__ __launch_bounds__(256) void k_colstats(const float* __restrict__ X, int R, int C,
                                                  float* __restrict__ st) {
  int c = blockIdx.x;
  float s = 0.f, q = 0.f;
  for (int r = threadIdx.x; r < R; r += 256) {
    float v = X[(size_t)r * C + c];
    s += v; q += v * v;
  }
  __shared__ float rs_[256], rq_[256];
  rs_[threadIdx.x] = s; rq_[threadIdx.x] = q;
  __syncthreads();
  for (int k = 128; k > 0; k >>= 1) {
    if (threadIdx.x < k) { rs_[threadIdx.x] += rs_[threadIdx.x + k]; rq_[threadIdx.x] += rq_[threadIdx.x + k]; }
    __syncthreads();
  }
  if (threadIdx.x == 0) {
    float m = rs_[0] / R;
    st[c] = m;
    st[C + c] = rq_[0] / R - m * m;
  }
}

template <int ACT>
__global__ void k_bnact(const float* __restrict__ X, float* __restrict__ Y,
                        const float* __restrict__ st, const float* __restrict__ sc,
                        const float* __restrict__ of, int Cmask, int n) {
  int i = blockIdx.x * 256 + threadIdx.x;
  if (i >= n) return;
  int C = Cmask + 1;
  int c = i & Cmask;
  float m = st[c], v = st[C + c];
  float y = (X[i] - m) * rsqrtf(v + EPSV) * sc[c] + of[c];
  Y[i] = ACT ? tanhf(y) : fmaxf(y, 0.0f);
}

// ---------------- generic GEMM ----------------
// OBF: 0=f32 row-major, 1=bf16 row-major,
//      2=bf16 decoder-gate layout [t][w128][b16][g4*4+j],
//      3=f32  encoder-gate layout [l][w64][b16][g4*4+j]
template <int OBF>
__global__ __launch_bounds__(256) void k_gemm(const float* __restrict__ Ap,
                                              const float* __restrict__ Bp,
                                              const float* __restrict__ bias,
                                              void* __restrict__ Cp, int M, int K, int N) {
  __shared__ float al[16 * 768];
  int row0 = blockIdx.x * 16;
  int c = blockIdx.y * 256 + threadIdx.x;
  for (int i = threadIdx.x; i < 16 * K; i += 256) al[i] = Ap[(size_t)row0 * K + i];
  __syncthreads();
  float acc[16];
  float bv = bias ? bias[c] : 0.0f;
#pragma unroll
  for (int j = 0; j < 16; ++j) acc[j] = bv;
  for (int k = 0; k < K; ++k) {
    float b = Bp[(size_t)k * N + c];
#pragma unroll
    for (int j = 0; j < 16; ++j) acc[j] += al[j * K + k] * b;
  }
  if (OBF == 0) {
    float* C = (float*)Cp;
#pragma unroll
    for (int j = 0; j < 16; ++j) C[(size_t)(row0 + j) * N + c] = acc[j];
  } else if (OBF == 1) {
    unsigned short* C = (unsigned short*)Cp;
#pragma unroll
    for (int j = 0; j < 16; ++j) C[(size_t)(row0 + j) * N + c] = f2b(acc[j]);
  } else if (OBF == 2) {
    unsigned short* C = (unsigned short*)Cp;
    int g = c >> 9, w = (c & 511) >> 2, jj = c & 3;
#pragma unroll
    for (int j = 0; j < 16; ++j) {
      int row = row0 + j;
      int b = row >> 9, t = row & 511;
      C[((size_t)t * 128 + w) * 256 + b * 16 + g * 4 + jj] = f2b(acc[j]);
    }
  } else {
    float* C = (float*)Cp;
    int g = c >> 8, w = (c & 255) >> 2, jj = c & 3;
#pragma unroll
    for (int j = 0; j < 16; ++j) {
      int row = row0 + j;
      int b = row >> 8, l = row & 255;
      C[((size_t)l * 64 + w) * 256 + b * 16 + g * 4 + jj] = acc[j];
    }
  }
}

// ---------------- duration cumsum ----------------
__global__ void k_cumsum(const float* __restrict__ dur, float* __restrict__ mid) {
  int b = threadIdx.x;
  if (b >= 16) return;
  float run = 0.f;
  for (int l = 0; l < 256; ++l) {
    float d = dur[b * 256 + l];
    run += d;
    mid[b * 256 + l] = run - 0.5f * d;
  }
}

// ---------------- persistent bi-LSTM encoder ----------------
// grid 128: wg<64 fwd, >=64 bwd. Each wg owns 4 h-cols (of 256). 256 threads.
// flags: per (dir,step) 8 counter lines (8 WGs each, target 8), lanes 0..7 poll one line each.
__global__ __launch_bounds__(256) void k_enc_lstm(const float* __restrict__ GFp,
                                                  const float* __restrict__ GBp,
                                                  const float* __restrict__ Wf,
                                                  const float* __restrict__ Wb,
                                                  float* __restrict__ enc,
                                                  const int* __restrict__ lengths,
                                                  unsigned int* __restrict__ cnt) {
  const int tid = threadIdx.x;
  const int wg = blockIdx.x;
  const int dir = wg >> 6;
  const int w = wg & 63;
  const float* Gpre = dir ? GBp : GFp;
  const float* W = dir ? Wb : Wf;
  unsigned int* c_self = cnt + (size_t)dir * 256 * 128;

  __shared__ __align__(16) float hs[16 * 264];
  __shared__ __align__(16) float wh[16 * 264];
  __shared__ float part[16 * 257];
  __shared__ float gl[256];
  __shared__ float cst[64];
  __shared__ int rs[16];

  for (int i = tid; i < 16 * 256; i += 256) {
    int gc = i >> 8, k = i & 255;
    int g = gc >> 2, j = gc & 3;
    wh[gc * 264 + k] = W[(size_t)(256 + k) * 1024 + g * 256 + (w * 4 + j)];
  }
  if (tid < 64) cst[tid] = 0.0f;
  __syncthreads();

  const int og = tid >> 4, s = tid & 15;
  const int bq = og >> 2, jj = og & 3;
  const int b_ = tid >> 4, j_ = (tid >> 2) & 3, g_ = tid & 3;

  for (int t = 0; t < 256; ++t) {
    const int l = dir ? (255 - t) : t;
    if (tid < 16) rs[tid] = (dir == 1) && (l >= lengths[tid] - 1);
    // prefetch this thread's precomputed gate value (independent of flag)
    float gpre = Gpre[((size_t)l * 64 + w) * 256 + b_ * 16 + g_ * 4 + j_];
    if (t > 0 && tid < 8) {  // 8 lanes, one counter line each; exec-mask loop -> wait = max
      const unsigned int* a = c_self + (size_t)(t - 1) * 128 + tid * 16;
      unsigned int gcount = 0;
      while (ldcnt(a) < 8u) {
        __builtin_amdgcn_s_sleep(2);
        if (++gcount > (1u << 16)) break;
      }
    }
    __syncthreads();
    if (t > 0) {
      const int lprev = dir ? (l + 1) : (l - 1);
      for (int i = tid; i < 16 * 128; i += 256) {
        int b = i >> 7, k2 = i & 127;
        float a0, a1;
        ldg_wt2(&enc[(size_t)(b * 256 + lprev) * 512 + dir * 256 + 2 * k2], a0, a1);
        if (rs[b]) { a0 = 0.0f; a1 = 0.0f; }
        hs[b * 264 + 2 * k2] = a0;
        hs[b * 264 + 2 * k2 + 1] = a1;
      }
    }
    __syncthreads();

    float acc[4][4];
#pragma unroll
    for (int a = 0; a < 4; ++a) { acc[a][0] = 0; acc[a][1] = 0; acc[a][2] = 0; acc[a][3] = 0; }
    if (t > 0) {
      const int b0 = bq * 4;
#pragma unroll
      for (int i = 0; i < 8; ++i) {
        int k2 = (i * 16 + s) * 2;
        float2 h0 = *(const float2*)&hs[(b0 + 0) * 264 + k2];
        float2 h1 = *(const float2*)&hs[(b0 + 1) * 264 + k2];
        float2 h2 = *(const float2*)&hs[(b0 + 2) * 264 + k2];
        float2 h3 = *(const float2*)&hs[(b0 + 3) * 264 + k2];
#pragma unroll
        for (int g = 0; g < 4; ++g) {
          float2 wv = *(const float2*)&wh[(g * 4 + jj) * 264 + k2];
          acc[0][g] += h0.x * wv.x + h0.y * wv.y;
          acc[1][g] += h1.x * wv.x + h1.y * wv.y;
          acc[2][g] += h2.x * wv.x + h2.y * wv.y;
          acc[3][g] += h3.x * wv.x + h3.y * wv.y;
        }
      }
    }
#pragma unroll
    for (int a = 0; a < 4; ++a)
#pragma unroll
      for (int g = 0; g < 4; ++g)
        part[s * 257 + ((bq * 4 + a) * 16 + jj * 4 + g)] = acc[a][g];
    __syncthreads();
    {
      float sum = gpre;
      if (t > 0) {
#pragma unroll
        for (int ss = 0; ss < 16; ++ss) sum += part[ss * 257 + tid];
      }
      gl[tid] = sum;
    }
    __syncthreads();
    if (tid < 64) {
      int b = tid >> 2, j = tid & 3;
      float gi = gl[b * 16 + j * 4 + 0];
      float gg = gl[b * 16 + j * 4 + 1];
      float gf = gl[b * 16 + j * 4 + 2];
      float go = gl[b * 16 + j * 4 + 3];
      float c = cst[tid];
      if (t == 0 || rs[b]) c = 0.0f;
      c = sigm(gf + 1.0f) * c + sigm(gi) * tanhf(gg);
      float h = sigm(go) * tanhf(c);
      cst[tid] = c;
      stg_wt(&enc[(size_t)(b * 256 + l) * 512 + dir * 256 + (w * 4 + j)], h);
    }
    __syncthreads();  // drains vmcnt(0) for all waves before publish
    if (tid == 0)
      __hip_atomic_fetch_add(c_self + (size_t)t * 128 + (w >> 3) * 16, 1u,
                             __ATOMIC_RELAXED, __HIP_MEMORY_SCOPE_AGENT);
  }
}

// ---------------- Gaussian-softmax upsampling ----------------
__global__ __launch_bounds__(256) void k_upsample(const float* __restrict__ mid,
                                                  const float* __restrict__ enc,
                                                  float* __restrict__ cond) {
  int blk = blockIdx.x;
  int b = blk >> 5, t0 = (blk & 31) * 16;
  int tid = threadIdx.x;
  __shared__ float wls[16][256];
  __shared__ float red[256];
  float mp = mid[b * 256 + tid];
  for (int tt = 0; tt < 16; ++tt) {
    float tpos = (float)(t0 + tt);
    float d = mp - tpos;
    float d2 = d * d * 0.1f;
    red[tid] = d2; __syncthreads();
    for (int k = 128; k > 0; k >>= 1) { if (tid < k) red[tid] = fminf(red[tid], red[tid + k]); __syncthreads(); }
    float mn = red[0]; __syncthreads();
    float e = expf(mn - d2);
    red[tid] = e; __syncthreads();
    for (int k = 128; k > 0; k >>= 1) { if (tid < k) red[tid] += red[tid + k]; __syncthreads(); }
    float sum = red[0]; __syncthreads();
    wls[tt][tid] = e / sum;
  }
  __syncthreads();
  float a0[16], a1[16];
#pragma unroll
  for (int i = 0; i < 16; ++i) { a0[i] = 0; a1[i] = 0; }
  for (int l = 0; l < 256; ++l) {
    float e0 = enc[(size_t)(b * 256 + l) * 512 + tid];
    float e1 = enc[(size_t)(b * 256 + l) * 512 + 256 + tid];
#pragma unroll
    for (int tt = 0; tt < 16; ++tt) { float wv = wls[tt][l]; a0[tt] += wv * e0; a1[tt] += wv * e1; }
  }
  for (int tt = 0; tt < 16; ++tt) {
    cond[(size_t)(b * 512 + t0 + tt) * 512 + tid] = a0[tt];
    cond[(size_t)(b * 512 + t0 + tt) * 512 + 256 + tid] = a1[tt];
  }
}

__global__ void k_concat(const float* __restrict__ cond, const float* __restrict__ p,
                         float* __restrict__ din) {
  size_t i = (size_t)blockIdx.x * 256 + threadIdx.x;
  int r = (int)(i / 768);
  int c = (int)(i % 768);
  din[i] = (c < 512) ? cond[(size_t)r * 512 + c] : p[(size_t)r * 256 + (c - 512)];
}

// ---------------- persistent 2-layer zoneout LSTM decoder ----------------
// 256 WGs: 0..127 layer1 (each owns 4 h-cols of 512), 128..255 layer2.
// flags: per step 8 counter lines (16 WGs each, target 16); lanes poll one line each.
#define LDHD 1032
__global__ __launch_bounds__(256) void k_dec_lstm(
    const unsigned short* __restrict__ D1x, const unsigned short* __restrict__ D2x,
    const float* __restrict__ W1, const float* __restrict__ W2,
    const void* __restrict__ zh1, const void* __restrict__ zc1,
    const void* __restrict__ zh2, const void* __restrict__ zc2,
    float* __restrict__ h1c, float* __restrict__ h1n,
    float* __restrict__ h2c, float* __restrict__ h2n,
    unsigned int* __restrict__ cnt1, unsigned int* __restrict__ cnt2,
    const int* __restrict__ flags) {
  const int tid = threadIdx.x;
  const int wg = blockIdx.x;
  const bool isL2 = wg >= 128;
  const int w = isL2 ? (wg - 128) : wg;

  __shared__ __align__(16) float hs[16 * LDHD];
  __shared__ __align__(16) float wh[16 * LDHD];
  __shared__ float part[16 * 257];
  __shared__ float gl[256];
  __shared__ float cst[64];

  const int mmode = flags[1];
  const int KK = isL2 ? 1024 : 512;
  const float* W = isL2 ? W2 : W1;

  for (int i = tid; i < 16 * KK; i += 256) {
    int gc = i / KK, k = i - gc * KK;
    int g = gc >> 2, j = gc & 3;
    wh[gc * LDHD + k] = W[(size_t)(768 + k) * 2048 + g * 512 + (w * 4 + j)];
  }
  if (tid < 64) cst[tid] = 0.0f;
  __syncthreads();

  const int og = tid >> 4, s = tid & 15;
  const int bq = og >> 2, jj = og & 3;
  const int SEGI2 = KK >> 5;
  const int b_ = tid >> 4, j_ = (tid >> 2) & 3, g_ = tid & 3;

  const void* zh = isL2 ? zh2 : zh1;
  const void* zc = isL2 ? zc2 : zc1;
  const unsigned short* Dx = isL2 ? D2x : D1x;
  float* hN = isL2 ? h2n : h1n;
  float* hC = isL2 ? h2c : h1c;

  for (int t = 0; t < 512; ++t) {
    // prefetch this thread's precomputed gate value (independent of flags)
    float dxv = b2f(Dx[((size_t)t * 128 + w) * 256 + b_ * 16 + g_ * 4 + j_]);
    {
      // one exec-masked spin: each lane polls at most one counter line
      const unsigned int* a = nullptr;
      if (isL2) {
        if (tid < 8) a = cnt1 + (size_t)t * 128 + tid * 16;
        else if (tid < 16 && t > 0) a = cnt2 + (size_t)(t - 1) * 128 + (tid - 8) * 16;
      } else if (t > 0 && tid < 8) {
        a = cnt1 + (size_t)(t - 1) * 128 + tid * 16;
      }
      if (a) {
        unsigned int gcount = 0;
        while (ldcnt(a) < 16u) {
          __builtin_amdgcn_s_sleep(2);
          if (++gcount > (1u << 16)) break;
        }
      }
    }
    __syncthreads();
    if (isL2) {
      for (int i = tid; i < 16 * 256; i += 256) {
        int b = i >> 8, k2 = i & 255;
        float a0, a1;
        ldg_wt2(&h1n[(size_t)(t * 16 + b) * 512 + 2 * k2], a0, a1);
        hs[b * LDHD + 2 * k2] = a0;
        hs[b * LDHD + 2 * k2 + 1] = a1;
      }
      if (t > 0) {
        for (int i = tid; i < 16 * 256; i += 256) {
          int b = i >> 8, k2 = i & 255;
          float a0, a1;
          ldg_wt2(&h2c[(size_t)((t - 1) * 16 + b) * 512 + 2 * k2], a0, a1);
          hs[b * LDHD + 512 + 2 * k2] = a0;
          hs[b * LDHD + 512 + 2 * k2 + 1] = a1;
        }
      } else {
        for (int i = tid; i < 16 * 512; i += 256) {
          int b = i >> 9, k = i & 511;
          hs[b * LDHD + 512 + k] = 0.0f;
        }
      }
    } else if (t > 0) {
      for (int i = tid; i < 16 * 256; i += 256) {
        int b = i >> 8, k2 = i & 255;
        float a0, a1;
        ldg_wt2(&h1c[(size_t)((t - 1) * 16 + b) * 512 + 2 * k2], a0, a1);
        hs[b * LDHD + 2 * k2] = a0;
        hs[b * LDHD + 2 * k2 + 1] = a1;
      }
    }
    __syncthreads();

    float acc[4][4];
#pragma unroll
    for (int a = 0; a < 4; ++a) { acc[a][0] = 0; acc[a][1] = 0; acc[a][2] = 0; acc[a][3] = 0; }
    const bool doDot = isL2 || (t > 0);
    if (doDot) {
      const int b0 = bq * 4;
      for (int i = 0; i < SEGI2; ++i) {
        int k2 = (i * 16 + s) * 2;
        float2 h0 = *(const float2*)&hs[(b0 + 0) * LDHD + k2];
        float2 h1 = *(const float2*)&hs[(b0 + 1) * LDHD + k2];
        float2 h2 = *(const float2*)&hs[(b0 + 2) * LDHD + k2];
        float2 h3 = *(const float2*)&hs[(b0 + 3) * LDHD + k2];
#pragma unroll
        for (int g = 0; g < 4; ++g) {
          float2 wv = *(const float2*)&wh[(g * 4 + jj) * LDHD + k2];
          acc[0][g] += h0.x * wv.x + h0.y * wv.y;
          acc[1][g] += h1.x * wv.x + h1.y * wv.y;
          acc[2][g] += h2.x * wv.x + h2.y * wv.y;
          acc[3][g] += h3.x * wv.x + h3.y * wv.y;
        }
      }
    }
#pragma unroll
    for (int a = 0; a < 4; ++a)
#pragma unroll
      for (int g = 0; g < 4; ++g)
        part[s * 257 + ((bq * 4 + a) * 16 + jj * 4 + g)] = acc[a][g];
    __syncthreads();
    {
      float sum = dxv;
      if (doDot) {
#pragma unroll
        for (int ss = 0; ss < 16; ++ss) sum += part[ss * 257 + tid];
      }
      gl[tid] = sum;
    }
    __syncthreads();
    if (tid < 64) {
      int b = tid >> 2, j = tid & 3;
      int colg = w * 4 + j;
      float gi = gl[b * 16 + j * 4 + 0];
      float gg = gl[b * 16 + j * 4 + 1];
      float gf = gl[b * 16 + j * 4 + 2];
      float go = gl[b * 16 + j * 4 + 3];
      float cold = (t == 0) ? 0.0f : cst[tid];
      float hold;
      if (isL2) hold = (t == 0) ? 0.0f : hs[b * LDHD + 512 + colg];
      else hold = (t == 0) ? 0.0f : hs[b * LDHD + colg];
      float nc = sigm(gf + 1.0f) * cold + sigm(gi) * tanhf(gg);
      float nh = sigm(go) * tanhf(nc);
      size_t mi = ((size_t)b * 512 + t) * 512 + colg;
      bool mh = mask_at(zh, mi, mmode);
      bool mc = mask_at(zc, mi, mmode);
      cst[tid] = mc ? cold : nc;
      stg_wt(&hN[(size_t)(t * 16 + b) * 512 + colg], nh);
      stg_wt(&hC[(size_t)(t * 16 + b) * 512 + colg], mh ? hold : nh);
    }
    __syncthreads();  // drains vmcnt(0) for all waves before publish
    if (tid == 0)
      __hip_atomic_fetch_add((isL2 ? cnt2 : cnt1) + (size_t)t * 128 + (w >> 4) * 16, 1u,
                             __ATOMIC_RELAXED, __HIP_MEMORY_SCOPE_AGENT);
  }
}

// ---------------- projection ----------------
__global__ __launch_bounds__(320) void k_proj(const float* __restrict__ cond,
                                              const float* __restrict__ h1n,
                                              const float* __restrict__ h2n,
                                              const float* __restrict__ pw,
                                              const float* __restrict__ pb,
                                              float* __restrict__ mel) {
  __shared__ float as_[4 * 1536];
  int r0 = blockIdx.x * 4;
  for (int i = threadIdx.x; i < 4 * 1536; i += 320) {
    int row = i / 1536, k = i % 1536;
    int r = r0 + row;
    int b = r >> 9, t = r & 511;
    float v;
    if (k < 512) v = cond[(size_t)r * 512 + k];
    else if (k < 1024) v = h1n[(size_t)(t * 16 + b) * 512 + (k - 512)];
    else v = h2n[(size_t)(t * 16 + b) * 512 + (k - 1024)];
    as_[i] = v;
  }
  __syncthreads();
  int row = threadIdx.x / 80, co = threadIdx.x % 80;
  float acc = pb[co];
  for (int k = 0; k < 1536; ++k) acc += as_[row * 1536 + k] * pw[(size_t)k * 80 + co];
  mel[(size_t)(r0 + row) * 80 + co] = acc;
}

// ---------------- k=5 conv ----------------
__global__ __launch_bounds__(256) void k_conv5(const float* __restrict__ X, int Cin,
                                               float* __restrict__ Y, int Cout,
                                               const float* __restrict__ Wc,
                                               const float* __restrict__ bias) {
  extern __shared__ float ys[];
  int blk = blockIdx.x;
  int b = blk >> 6, t0 = (blk & 63) * 8;
  for (int i = threadIdx.x; i < 12 * Cin; i += 256) {
    int rr = i / Cin, ci = i % Cin;
    int tt = t0 - 2 + rr;
    ys[i] = (tt >= 0 && tt < 512) ? X[(size_t)(b * 512 + tt) * Cin + ci] : 0.0f;
  }
  __syncthreads();
  for (int co = threadIdx.x; co < Cout; co += 256) {
    float acc[8];
    float bv = bias ? bias[co] : 0.0f;
#pragma unroll
    for (int j = 0; j < 8; ++j) acc[j] = bv;
    for (int dt = 0; dt < 5; ++dt)
      for (int ci = 0; ci < Cin; ++ci) {
        float wv = Wc[(size_t)(dt * Cin + ci) * Cout + co];
#pragma unroll
        for (int j = 0; j < 8; ++j) acc[j] += ys[(j + dt) * Cin + ci] * wv;
      }
#pragma unroll
    for (int j = 0; j < 8; ++j) Y[(size_t)(b * 512 + t0 + j) * Cout + co] = acc[j];
  }
}

__global__ void k_out(const float* __restrict__ mel, const float* __restrict__ res,
                      void* __restrict__ out, const int* __restrict__ flags) {
  int i = blockIdx.x * 256 + threadIdx.x;
  float m = mel[i];
  float f = m + res[i];
  if (flags[0]) {
    ((float*)out)[i] = m;
    ((float*)out)[655360 + i] = f;
  } else {
    unsigned short* o = (unsigned short*)out;
    o[i] = f2b(m);
    o[655360 + i] = f2b(f);
  }
}

// ---------------- host launch ----------------
extern "C" void kernel_launch(void* const* d_in, const int* in_sizes, int n_in,
                              void* d_out, int out_size, void* d_ws, size_t ws_size,
                              hipStream_t stream) {
  char* ws = (char*)d_ws;
  size_t o = 0;
  auto A_ = [&](size_t nb) { size_t r = o; o += (nb + 255) & ~(size_t)255; return r; };
  const size_t FLAGS = A_(256);
  // sync: encoder 2*256 steps * 8 lines * 64B = 256KB; decoder 2 * (512*8*64B=256KB)
  const size_t SYNC = A_(786432);
  const size_t STATS = A_(4096);
  const size_t C_MELS = A_(655360ull * 4), C_DUR = A_(4096 * 4), C_EMB = A_(65536 * 4),
               C_ECW = A_(589824ull * 4), C_EBS = A_(768 * 4), C_EBO = A_(768 * 4),
               C_LFW = A_(524288ull * 4), C_LFB = A_(1024 * 4), C_LBW = A_(524288ull * 4),
               C_LBB = A_(1024 * 4), C_PW1 = A_(20480 * 4), C_P1S = A_(256 * 4),
               C_P1O = A_(256 * 4), C_PW2 = A_(65536 * 4), C_P2S = A_(256 * 4),
               C_P2O = A_(256 * 4), C_DW1 = A_(2621440ull * 4), C_DB1 = A_(2048 * 4),
               C_DW2 = A_(3670016ull * 4), C_DB2 = A_(2048 * 4), C_PRW = A_(122880ull * 4),
               C_PRB = A_(512), C_W0 = A_(204800ull * 4), C_WM = A_(3932160ull * 4),
               C_W4 = A_(204800ull * 4), C_B4 = A_(512), C_PBS = A_(2048 * 4),
               C_PBO = A_(2048 * 4);
  const size_t R1 = A_(16777216), R2 = A_(16777216), R3 = A_(16777216), R4 = A_(16777216),
               MID = A_(4096 * 4), R5 = A_(16777216), R6 = A_(16777216), R7 = A_(25165824),
               D1X = A_(33554432), D2X = A_(33554432), MELP = A_(2621440);
  const size_t XA = R1, XB = R1 + 4194304, H1C = R1;
  const size_t GF = R2, H2C = R2;
  const size_t GB = R3, H1N = R3;
  const size_t ENC = R4, H2N = R4;
  const size_t COND = R5, PA = R5;
  const size_t PREA = R6, PREB = R6 + 8388608, PB = R6;
  const size_t DECIN = R7, RESID = R7;

  auto F = [&](size_t off) { return (float*)(ws + off); };
  int* flags = (int*)(ws + FLAGS);
  unsigned int* cntE = (unsigned int*)(ws + SYNC);
  unsigned int* cnt1 = (unsigned int*)(ws + SYNC + 262144);
  unsigned int* cnt2 = (unsigned int*)(ws + SYNC + 524288);

  hipMemsetAsync(ws + SYNC, 0, 786432, stream);
  k_detect<<<1, 256, 0, stream>>>(d_in[8], d_in[4], flags);

  struct CV { int idx; size_t off; int n; };
  const CV cvs[] = {
      {2, C_MELS, 655360}, {3, C_DUR, 4096}, {8, C_EMB, 65536}, {9, C_ECW, 589824},
      {10, C_EBS, 768}, {11, C_EBO, 768}, {12, C_LFW, 524288}, {13, C_LFB, 1024},
      {14, C_LBW, 524288}, {15, C_LBB, 1024}, {16, C_PW1, 20480}, {17, C_P1S, 256},
      {18, C_P1O, 256}, {19, C_PW2, 65536}, {20, C_P2S, 256}, {21, C_P2O, 256},
      {22, C_DW1, 2621440}, {23, C_DB1, 2048}, {24, C_DW2, 3670016}, {25, C_DB2, 2048},
      {26, C_PRW, 122880}, {27, C_PRB, 80}, {28, C_W0, 204800}, {29, C_WM, 3932160},
      {30, C_W4, 204800}, {31, C_B4, 80}, {32, C_PBS, 2048}, {33, C_PBO, 2048}};
  for (int i = 0; i < (int)(sizeof(cvs) / sizeof(cvs[0])); ++i)
    k_cvt<<<(cvs[i].n + 255) / 256, 256, 0, stream>>>(d_in[cvs[i].idx], F(cvs[i].off), cvs[i].n, flags);

  k_embed<<<4096, 256, 0, stream>>>((const int*)d_in[0], F(C_EMB), F(XA));
  for (int i = 0; i < 3; ++i) {
    k_conv3<<<1024, 256, 0, stream>>>(F(XA), F(C_ECW) + (size_t)i * 196608, F(XB));
    k_colstats<<<256, 256, 0, stream>>>(F(XB), 4096, 256, F(STATS));
    k_bnact<0><<<4096, 256, 0, stream>>>(F(XB), F(XA), F(STATS), F(C_EBS) + i * 256, F(C_EBO) + i * 256, 255, 1048576);
  }
  k_gemm<3><<<dim3(256, 4), 256, 0, stream>>>(F(XA), F(C_LFW), F(C_LFB), (void*)(ws + GF), 4096, 256, 1024);
  k_gemm<3><<<dim3(256, 4), 256, 0, stream>>>(F(XA), F(C_LBW), F(C_LBB), (void*)(ws + GB), 4096, 256, 1024);
  k_cumsum<<<1, 64, 0, stream>>>(F(C_DUR), F(MID));
  k_enc_lstm<<<128, 256, 0, stream>>>(F(GF), F(GB), F(C_LFW), F(C_LBW), F(ENC), (const int*)d_in[1], cntE);
  k_upsample<<<512, 256, 0, stream>>>(F(MID), F(ENC), F(COND));

  k_gemm<0><<<dim3(512, 1), 256, 0, stream>>>(F(C_MELS), F(C_PW1), nullptr, (void*)(ws + PREA), 8192, 80, 256);
  k_colstats<<<256, 256, 0, stream>>>(F(PREA), 8192, 256, F(STATS));
  k_bnact<0><<<8192, 256, 0, stream>>>(F(PREA), F(PREB), F(STATS), F(C_P1S), F(C_P1O), 255, 2097152);
  k_gemm<0><<<dim3(512, 1), 256, 0, stream>>>(F(PREB), F(C_PW2), nullptr, (void*)(ws + PREA), 8192, 256, 256);
  k_colstats<<<256, 256, 0, stream>>>(F(PREA), 8192, 256, F(STATS));
  k_bnact<0><<<8192, 256, 0, stream>>>(F(PREA), F(PREB), F(STATS), F(C_P2S), F(C_P2O), 255, 2097152);

  k_concat<<<24576, 256, 0, stream>>>(F(COND), F(PREB), F(DECIN));
  k_gemm<2><<<dim3(512, 8), 256, 0, stream>>>(F(DECIN), F(C_DW1), F(C_DB1), (void*)(ws + D1X), 8192, 768, 2048);
  k_gemm<2><<<dim3(512, 8), 256, 0, stream>>>(F(DECIN), F(C_DW2), F(C_DB2), (void*)(ws + D2X), 8192, 768, 2048);
  k_dec_lstm<<<256, 256, 0, stream>>>((const unsigned short*)(ws + D1X), (const unsigned short*)(ws + D2X),
                                      F(C_DW1), F(C_DW2), d_in[4], d_in[5], d_in[6], d_in[7],
                                      F(H1C), F(H1N), F(H2C), F(H2N), cnt1, cnt2, flags);
  k_proj<<<2048, 320, 0, stream>>>(F(COND), F(H1N), F(H2N), F(C_PRW), F(C_PRB), F(MELP));

  k_conv5<<<1024, 256, 12 * 80 * 4, stream>>>(F(MELP), 80, F(PA), 512, F(C_W0), nullptr);
  k_colstats<<<512, 256, 0, stream>>>(F(PA), 8192, 512, F(STATS));
  k_bnact<1><<<16384, 256, 0, stream>>>(F(PA), F(PB), F(STATS), F(C_PBS), F(C_PBO), 511, 4194304);
  for (int i = 0; i < 3; ++i) {
    k_conv5<<<1024, 256, 12 * 512 * 4, stream>>>(F(PB), 512, F(PA), 512, F(C_WM) + (size_t)i * 1310720, nullptr);
    k_colstats<<<512, 256, 0, stream>>>(F(PA), 8192, 512, F(STATS));
    k_bnact<1><<<16384, 256, 0, stream>>>(F(PA), F(PB), F(STATS), F(C_PBS) + (i + 1) * 512, F(C_PBO) + (i + 1) * 512, 511, 4194304);
  }
  k_conv5<<<1024, 256, 12 * 512 * 4, stream>>>(F(PB), 512, F(RESID), 80, F(C_W4), F(C_B4));
  k_out<<<2560, 256, 0, stream>>>(F(MELP), F(RESID), d_out, flags);
}

// Round 5
// 16902.844 us; speedup vs baseline: 2.1288x; 1.1640x over previous
//
#include <hip/hip_runtime.h>

#define EPSV 1e-5f

typedef unsigned int uivec4 __attribute__((ext_vector_type(4)));

__device__ __forceinline__ float b2f(unsigned short u) {
  unsigned int x = ((unsigned int)u) << 16;
  return __uint_as_float(x);
}
__device__ __forceinline__ unsigned short f2b(float f) {
  unsigned int x = __float_as_uint(f);
  unsigned int r = (x + 0x7FFFu + ((x >> 16) & 1u)) >> 16;
  return (unsigned short)r;
}
__device__ __forceinline__ float sigm(float x) { return 1.0f / (1.0f + expf(-x)); }

// ---- coherence-point (device-coherent) access helpers: bypass L1+L2 both ways ----
__device__ __forceinline__ void stg_bf16(unsigned short* p, float v) {
  unsigned short h = f2b(v);
  asm volatile("global_store_short %0, %1, off sc0 sc1" ::"v"(p), "v"(h) : "memory");
}
__device__ __forceinline__ void ldg2_sc(const unsigned short* p0, const unsigned short* p1,
                                        uivec4& a, uivec4& b) {
  asm volatile(
      "global_load_dwordx4 %0, %2, off sc0 sc1\n\t"
      "global_load_dwordx4 %1, %3, off sc0 sc1\n\t"
      "s_waitcnt vmcnt(0)"
      : "=&v"(a), "=&v"(b)
      : "v"(p0), "v"(p1)
      : "memory");
}
__device__ __forceinline__ void ldg4_sc(const unsigned short* p0, const unsigned short* p1,
                                        const unsigned short* p2, const unsigned short* p3,
                                        uivec4& a, uivec4& b, uivec4& c, uivec4& d) {
  asm volatile(
      "global_load_dwordx4 %0, %4, off sc0 sc1\n\t"
      "global_load_dwordx4 %1, %5, off sc0 sc1\n\t"
      "global_load_dwordx4 %2, %6, off sc0 sc1\n\t"
      "global_load_dwordx4 %3, %7, off sc0 sc1\n\t"
      "s_waitcnt vmcnt(0)"
      : "=&v"(a), "=&v"(b), "=&v"(c), "=&v"(d)
      : "v"(p0), "v"(p1), "v"(p2), "v"(p3)
      : "memory");
}
__device__ __forceinline__ void ldg8_sc(const unsigned short* p0, const unsigned short* p1,
                                        const unsigned short* p2, const unsigned short* p3,
                                        const unsigned short* p4, const unsigned short* p5,
                                        const unsigned short* p6, const unsigned short* p7,
                                        uivec4& a, uivec4& b, uivec4& c, uivec4& d,
                                        uivec4& e, uivec4& f, uivec4& g, uivec4& h) {
  asm volatile(
      "global_load_dwordx4 %0, %8, off sc0 sc1\n\t"
      "global_load_dwordx4 %1, %9, off sc0 sc1\n\t"
      "global_load_dwordx4 %2, %10, off sc0 sc1\n\t"
      "global_load_dwordx4 %3, %11, off sc0 sc1\n\t"
      "global_load_dwordx4 %4, %12, off sc0 sc1\n\t"
      "global_load_dwordx4 %5, %13, off sc0 sc1\n\t"
      "global_load_dwordx4 %6, %14, off sc0 sc1\n\t"
      "global_load_dwordx4 %7, %15, off sc0 sc1\n\t"
      "s_waitcnt vmcnt(0)"
      : "=&v"(a), "=&v"(b), "=&v"(c), "=&v"(d), "=&v"(e), "=&v"(f), "=&v"(g), "=&v"(h)
      : "v"(p0), "v"(p1), "v"(p2), "v"(p3), "v"(p4), "v"(p5), "v"(p6), "v"(p7)
      : "memory");
}
// unpack 8 packed bf16 (one 16B load) -> 8 f32 in LDS
__device__ __forceinline__ void bf8_to_lds(float* dst, uivec4 u) {
  float2 p;
  p.x = __uint_as_float(u.x << 16); p.y = __uint_as_float(u.x & 0xFFFF0000u);
  *(float2*)(dst + 0) = p;
  p.x = __uint_as_float(u.y << 16); p.y = __uint_as_float(u.y & 0xFFFF0000u);
  *(float2*)(dst + 2) = p;
  p.x = __uint_as_float(u.z << 16); p.y = __uint_as_float(u.z & 0xFFFF0000u);
  *(float2*)(dst + 4) = p;
  p.x = __uint_as_float(u.w << 16); p.y = __uint_as_float(u.w & 0xFFFF0000u);
  *(float2*)(dst + 6) = p;
}
__device__ __forceinline__ unsigned int ldcnt(const unsigned int* p) {
  return __hip_atomic_load(p, __ATOMIC_RELAXED, __HIP_MEMORY_SCOPE_AGENT);
}

// ---------------- dtype detection ----------------
__global__ void k_detect(const void* __restrict__ embp, const void* __restrict__ zmp,
                         int* __restrict__ flags) {
  __shared__ int sh[4];
  int tid = threadIdx.x;
  if (tid < 4) sh[tid] = 0;
  __syncthreads();
  const unsigned short* u = (const unsigned short*)embp;
  int bad = 0;
  for (int i = tid; i < 4096; i += 256) {
    float f = fabsf(b2f(u[i]));
    if (!(f < 1e10f)) bad = 1;
  }
  if (bad) atomicAdd(&sh[3], 1);
  const unsigned char* p = (const unsigned char*)zmp;
  int codd = 0, c0 = 0, c1v = 0;
  for (int i = tid; i < 65536; i += 256) {
    unsigned char v = p[i];
    if (v) {
      if (i & 1) codd++;
      if ((i & 3) == 0) c0++;
      if (v == 1) c1v++;
    }
  }
  atomicAdd(&sh[0], codd); atomicAdd(&sh[1], c0); atomicAdd(&sh[2], c1v);
  __syncthreads();
  if (tid == 0) {
    flags[0] = sh[3] ? 1 : 0;
    int mode;
    if (sh[0] == 0) mode = 1;
    else if (sh[2] > 0) mode = 0;
    else if (sh[1] == 0) mode = 2;
    else mode = 3;
    flags[1] = mode;
  }
}

__global__ void k_cvt(const void* __restrict__ src, float* __restrict__ dst, int n,
                      const int* __restrict__ flags) {
  int i = blockIdx.x * 256 + threadIdx.x;
  if (i >= n) return;
  if (flags[0]) dst[i] = ((const float*)src)[i];
  else dst[i] = b2f(((const unsigned short*)src)[i]);
}

__device__ __forceinline__ bool mask_at(const void* p, size_t i, int mode) {
  switch (mode) {
    case 0: return ((const unsigned char*)p)[i] != 0;
    case 1: return ((const int*)p)[i] != 0;
    case 2: return ((const float*)p)[i] != 0.0f;
    default: return ((const unsigned short*)p)[i] != 0;
  }
}

// ---------------- embedding ----------------
__global__ void k_embed(const int* __restrict__ ph, const float* __restrict__ emb,
                        float* __restrict__ X) {
  int bl = blockIdx.x;
  int p = ph[bl];
  X[(size_t)bl * 256 + threadIdx.x] = emb[(size_t)p * 256 + threadIdx.x];
}

// ---------------- k=3 conv, E=256 -> E=256, SAME ----------------
__global__ __launch_bounds__(256) void k_conv3(const float* __restrict__ X,
                                               const float* __restrict__ Wc,
                                               float* __restrict__ Y) {
  __shared__ float xs[6 * 256];
  int blk = blockIdx.x;
  int b = blk >> 6, l0 = (blk & 63) * 4;
  for (int i = threadIdx.x; i < 6 * 256; i += 256) {
    int dl = i >> 8, ci = i & 255;
    int ll = l0 - 1 + dl;
    xs[i] = (ll >= 0 && ll < 256) ? X[(size_t)(b * 256 + ll) * 256 + ci] : 0.0f;
  }
  __syncthreads();
  int co = threadIdx.x;
  float acc[4] = {0.f, 0.f, 0.f, 0.f};
  for (int i = 0; i < 768; ++i) {
    int d = i >> 8, ci = i & 255;
    float wv = Wc[(size_t)i * 256 + co];
#pragma unroll
    for (int j = 0; j < 4; ++j) acc[j] += xs[(d + j) * 256 + ci] * wv;
  }
#pragma unroll
  for (int j = 0; j < 4; ++j) Y[(size_t)(b * 256 + l0 + j) * 256 + co] = acc[j];
}

// ---------------- per-channel mean/var ----------------
__global__ __launch_bounds__(256) void k_colstats(const float* __restrict__ X, int R, int C,
                                                  float* __restrict__ st) {
  int c = blockIdx.x;
  float s = 0.f, q = 0.f;
  for (int r = threadIdx.x; r < R; r += 256) {
    float v = X[(size_t)r * C + c];
    s += v; q += v * v;
  }
  __shared__ float rs_[256], rq_[256];
  rs_[threadIdx.x] = s; rq_[threadIdx.x] = q;
  __syncthreads();
  for (int k = 128; k > 0; k >>= 1) {
    if (threadIdx.x < k) { rs_[threadIdx.x] += rs_[threadIdx.x + k]; rq_[threadIdx.x] += rq_[threadIdx.x + k]; }
    __syncthreads();
  }
  if (threadIdx.x == 0) {
    float m = rs_[0] / R;
    st[c] = m;
    st[C + c] = rq_[0] / R - m * m;
  }
}

template <int ACT>
__global__ void k_bnact(const float* __restrict__ X, float* __restrict__ Y,
                        const float* __restrict__ st, const float* __restrict__ sc,
                        const float* __restrict__ of, int Cmask, int n) {
  int i = blockIdx.x * 256 + threadIdx.x;
  if (i >= n) return;
  int C = Cmask + 1;
  int c = i & Cmask;
  float m = st[c], v = st[C + c];
  float y = (X[i] - m) * rsqrtf(v + EPSV) * sc[c] + of[c];
  Y[i] = ACT ? tanhf(y) : fmaxf(y, 0.0f);
}

// ---------------- generic GEMM ----------------
// OBF: 0=f32 row-major, 1=bf16 row-major,
//      2=bf16 decoder-gate layout [t][w128][b16][g4*4+j],
//      3=f32  encoder-gate layout [l][w64][b16][g4*4+j]
template <int OBF>
__global__ __launch_bounds__(256) void k_gemm(const float* __restrict__ Ap,
                                              const float* __restrict__ Bp,
                                              const float* __restrict__ bias,
                                              void* __restrict__ Cp, int M, int K, int N) {
  __shared__ float al[16 * 768];
  int row0 = blockIdx.x * 16;
  int c = blockIdx.y * 256 + threadIdx.x;
  for (int i = threadIdx.x; i < 16 * K; i += 256) al[i] = Ap[(size_t)row0 * K + i];
  __syncthreads();
  float acc[16];
  float bv = bias ? bias[c] : 0.0f;
#pragma unroll
  for (int j = 0; j < 16; ++j) acc[j] = bv;
  for (int k = 0; k < K; ++k) {
    float b = Bp[(size_t)k * N + c];
#pragma unroll
    for (int j = 0; j < 16; ++j) acc[j] += al[j * K + k] * b;
  }
  if (OBF == 0) {
    float* C = (float*)Cp;
#pragma unroll
    for (int j = 0; j < 16; ++j) C[(size_t)(row0 + j) * N + c] = acc[j];
  } else if (OBF == 1) {
    unsigned short* C = (unsigned short*)Cp;
#pragma unroll
    for (int j = 0; j < 16; ++j) C[(size_t)(row0 + j) * N + c] = f2b(acc[j]);
  } else if (OBF == 2) {
    unsigned short* C = (unsigned short*)Cp;
    int g = c >> 9, w = (c & 511) >> 2, jj = c & 3;
#pragma unroll
    for (int j = 0; j < 16; ++j) {
      int row = row0 + j;
      int b = row >> 9, t = row & 511;
      C[((size_t)t * 128 + w) * 256 + b * 16 + g * 4 + jj] = f2b(acc[j]);
    }
  } else {
    float* C = (float*)Cp;
    int g = c >> 8, w = (c & 255) >> 2, jj = c & 3;
#pragma unroll
    for (int j = 0; j < 16; ++j) {
      int row = row0 + j;
      int b = row >> 8, l = row & 255;
      C[((size_t)l * 64 + w) * 256 + b * 16 + g * 4 + jj] = acc[j];
    }
  }
}

// ---------------- duration cumsum ----------------
__global__ void k_cumsum(const float* __restrict__ dur, float* __restrict__ mid) {
  int b = threadIdx.x;
  if (b >= 16) return;
  float run = 0.f;
  for (int l = 0; l < 256; ++l) {
    float d = dur[b * 256 + l];
    run += d;
    mid[b * 256 + l] = run - 0.5f * d;
  }
}

// ---------------- persistent bi-LSTM encoder ----------------
// grid 128: wg<64 fwd, >=64 bwd. Each wg owns 4 h-cols (of 256). 256 threads.
// State exchange: bf16 broadcast encB[dir][l][b][256] via sc0/sc1; f32 enc plain (for upsample).
__global__ __launch_bounds__(256) void k_enc_lstm(const float* __restrict__ GFp,
                                                  const float* __restrict__ GBp,
                                                  const float* __restrict__ Wf,
                                                  const float* __restrict__ Wb,
                                                  float* __restrict__ enc,
                                                  unsigned short* __restrict__ encB,
                                                  const int* __restrict__ lengths,
                                                  unsigned int* __restrict__ cnt) {
  const int tid = threadIdx.x;
  const int wg = blockIdx.x;
  const int dir = wg >> 6;
  const int w = wg & 63;
  const float* Gpre = dir ? GBp : GFp;
  const float* W = dir ? Wb : Wf;
  unsigned int* c_self = cnt + (size_t)dir * 256 * 128;

  __shared__ __align__(16) float hs[16 * 264];
  __shared__ __align__(16) float wh[16 * 264];
  __shared__ float part[16 * 257];
  __shared__ float gl[256];
  __shared__ float cst[64];
  __shared__ int rs[16];

  for (int i = tid; i < 16 * 256; i += 256) {
    int gc = i >> 8, k = i & 255;
    int g = gc >> 2, j = gc & 3;
    wh[gc * 264 + k] = W[(size_t)(256 + k) * 1024 + g * 256 + (w * 4 + j)];
  }
  if (tid < 64) cst[tid] = 0.0f;
  __syncthreads();

  const int og = tid >> 4, s = tid & 15;
  const int bq = og >> 2, jj = og & 3;
  const int b_ = tid >> 4, j_ = (tid >> 2) & 3, g_ = tid & 3;

  for (int t = 0; t < 256; ++t) {
    const int l = dir ? (255 - t) : t;
    if (tid < 16) rs[tid] = (dir == 1) && (l >= lengths[tid] - 1);
    float gpre = Gpre[((size_t)l * 64 + w) * 256 + b_ * 16 + g_ * 4 + j_];
    if (t > 0 && tid < 8) {
      const unsigned int* a = c_self + (size_t)(t - 1) * 128 + tid * 16;
      unsigned int gcount = 0;
      while (ldcnt(a) < 8u) {
        __builtin_amdgcn_s_sleep(2);
        if (++gcount > (1u << 16)) break;
      }
    }
    __syncthreads();
    if (t > 0) {
      const int lprev = dir ? (l + 1) : (l - 1);
      int b = tid >> 4, k0 = (tid & 15) * 16;
      const unsigned short* p = encB + ((size_t)dir << 20) + (((size_t)lprev * 16 + b) << 8) + k0;
      uivec4 a0, a1;
      ldg2_sc(p, p + 8, a0, a1);
      if (rs[b]) {
        a0.x = a0.y = a0.z = a0.w = 0u;
        a1.x = a1.y = a1.z = a1.w = 0u;
      }
      float* d = &hs[b * 264 + k0];
      bf8_to_lds(d, a0);
      bf8_to_lds(d + 8, a1);
    }
    __syncthreads();

    float acc[4][4];
#pragma unroll
    for (int a = 0; a < 4; ++a) { acc[a][0] = 0; acc[a][1] = 0; acc[a][2] = 0; acc[a][3] = 0; }
    if (t > 0) {
      const int b0 = bq * 4;
#pragma unroll
      for (int i = 0; i < 8; ++i) {
        int k2 = (i * 16 + s) * 2;
        float2 h0 = *(const float2*)&hs[(b0 + 0) * 264 + k2];
        float2 h1 = *(const float2*)&hs[(b0 + 1) * 264 + k2];
        float2 h2 = *(const float2*)&hs[(b0 + 2) * 264 + k2];
        float2 h3 = *(const float2*)&hs[(b0 + 3) * 264 + k2];
#pragma unroll
        for (int g = 0; g < 4; ++g) {
          float2 wv = *(const float2*)&wh[(g * 4 + jj) * 264 + k2];
          acc[0][g] += h0.x * wv.x + h0.y * wv.y;
          acc[1][g] += h1.x * wv.x + h1.y * wv.y;
          acc[2][g] += h2.x * wv.x + h2.y * wv.y;
          acc[3][g] += h3.x * wv.x + h3.y * wv.y;
        }
      }
    }
#pragma unroll
    for (int a = 0; a < 4; ++a)
#pragma unroll
      for (int g = 0; g < 4; ++g)
        part[s * 257 + ((bq * 4 + a) * 16 + jj * 4 + g)] = acc[a][g];
    __syncthreads();
    {
      float sum = gpre;
      if (t > 0) {
#pragma unroll
        for (int ss = 0; ss < 16; ++ss) sum += part[ss * 257 + tid];
      }
      gl[tid] = sum;
    }
    __syncthreads();
    if (tid < 64) {
      int b = tid >> 2, j = tid & 3;
      float gi = gl[b * 16 + j * 4 + 0];
      float gg = gl[b * 16 + j * 4 + 1];
      float gf = gl[b * 16 + j * 4 + 2];
      float go = gl[b * 16 + j * 4 + 3];
      float c = cst[tid];
      if (t == 0 || rs[b]) c = 0.0f;
      c = sigm(gf + 1.0f) * c + sigm(gi) * tanhf(gg);
      float h = sigm(go) * tanhf(c);
      cst[tid] = c;
      enc[(size_t)(b * 256 + l) * 512 + dir * 256 + (w * 4 + j)] = h;  // plain, cross-kernel
      stg_bf16(&encB[((size_t)dir << 20) + (((size_t)l * 16 + b) << 8) + (w * 4 + j)], h);
    }
    __syncthreads();
    if (tid == 0) {
      asm volatile("s_waitcnt vmcnt(0)" ::: "memory");
      __hip_atomic_fetch_add(c_self + (size_t)t * 128 + (w >> 3) * 16, 1u,
                             __ATOMIC_RELAXED, __HIP_MEMORY_SCOPE_AGENT);
    }
  }
}

// ---------------- Gaussian-softmax upsampling ----------------
__global__ __launch_bounds__(256) void k_upsample(const float* __restrict__ mid,
                                                  const float* __restrict__ enc,
                                                  float* __restrict__ cond) {
  int blk = blockIdx.x;
  int b = blk >> 5, t0 = (blk & 31) * 16;
  int tid = threadIdx.x;
  __shared__ float wls[16][256];
  __shared__ float red[256];
  float mp = mid[b * 256 + tid];
  for (int tt = 0; tt < 16; ++tt) {
    float tpos = (float)(t0 + tt);
    float d = mp - tpos;
    float d2 = d * d * 0.1f;
    red[tid] = d2; __syncthreads();
    for (int k = 128; k > 0; k >>= 1) { if (tid < k) red[tid] = fminf(red[tid], red[tid + k]); __syncthreads(); }
    float mn = red[0]; __syncthreads();
    float e = expf(mn - d2);
    red[tid] = e; __syncthreads();
    for (int k = 128; k > 0; k >>= 1) { if (tid < k) red[tid] += red[tid + k]; __syncthreads(); }
    float sum = red[0]; __syncthreads();
    wls[tt][tid] = e / sum;
  }
  __syncthreads();
  float a0[16], a1[16];
#pragma unroll
  for (int i = 0; i < 16; ++i) { a0[i] = 0; a1[i] = 0; }
  for (int l = 0; l < 256; ++l) {
    float e0 = enc[(size_t)(b * 256 + l) * 512 + tid];
    float e1 = enc[(size_t)(b * 256 + l) * 512 + 256 + tid];
#pragma unroll
    for (int tt = 0; tt < 16; ++tt) { float wv = wls[tt][l]; a0[tt] += wv * e0; a1[tt] += wv * e1; }
  }
  for (int tt = 0; tt < 16; ++tt) {
    cond[(size_t)(b * 512 + t0 + tt) * 512 + tid] = a0[tt];
    cond[(size_t)(b * 512 + t0 + tt) * 512 + 256 + tid] = a1[tt];
  }
}

__global__ void k_concat(const float* __restrict__ cond, const float* __restrict__ p,
                         float* __restrict__ din) {
  size_t i = (size_t)blockIdx.x * 256 + threadIdx.x;
  int r = (int)(i / 768);
  int c = (int)(i % 768);
  din[i] = (c < 512) ? cond[(size_t)r * 512 + c] : p[(size_t)r * 256 + (c - 512)];
}

// ---------------- persistent 2-layer zoneout LSTM decoder ----------------
// 256 WGs: 0..127 layer1 (each owns 4 h-cols of 512), 128..255 layer2.
// bf16 broadcast: h1cB (L1 dot), h1nB+h2cB (L2 dot); f32 h1n/h2n plain for k_proj.
#define LDHD 1032
__global__ __launch_bounds__(256) void k_dec_lstm(
    const unsigned short* __restrict__ D1x, const unsigned short* __restrict__ D2x,
    const float* __restrict__ W1, const float* __restrict__ W2,
    const void* __restrict__ zh1, const void* __restrict__ zc1,
    const void* __restrict__ zh2, const void* __restrict__ zc2,
    unsigned short* __restrict__ h1cB, unsigned short* __restrict__ h1nB,
    unsigned short* __restrict__ h2cB,
    float* __restrict__ h1n, float* __restrict__ h2n,
    unsigned int* __restrict__ cnt1, unsigned int* __restrict__ cnt2,
    const int* __restrict__ flags) {
  const int tid = threadIdx.x;
  const int wg = blockIdx.x;
  const bool isL2 = wg >= 128;
  const int w = isL2 ? (wg - 128) : wg;

  __shared__ __align__(16) float hs[16 * LDHD];
  __shared__ __align__(16) float wh[16 * LDHD];
  __shared__ float part[16 * 257];
  __shared__ float gl[256];
  __shared__ float cst[64];
  __shared__ float hst[64];

  const int mmode = flags[1];
  const int KK = isL2 ? 1024 : 512;
  const float* W = isL2 ? W2 : W1;

  for (int i = tid; i < 16 * KK; i += 256) {
    int gc = i / KK, k = i - gc * KK;
    int g = gc >> 2, j = gc & 3;
    wh[gc * LDHD + k] = W[(size_t)(768 + k) * 2048 + g * 512 + (w * 4 + j)];
  }
  if (tid < 64) { cst[tid] = 0.0f; hst[tid] = 0.0f; }
  __syncthreads();

  const int og = tid >> 4, s = tid & 15;
  const int bq = og >> 2, jj = og & 3;
  const int SEGI2 = KK >> 5;
  const int b_ = tid >> 4, j_ = (tid >> 2) & 3, g_ = tid & 3;

  const void* zh = isL2 ? zh2 : zh1;
  const void* zc = isL2 ? zc2 : zc1;
  const unsigned short* Dx = isL2 ? D2x : D1x;
  float* hN = isL2 ? h2n : h1n;
  unsigned short* hCB = isL2 ? h2cB : h1cB;

  for (int t = 0; t < 512; ++t) {
    float dxv = b2f(Dx[((size_t)t * 128 + w) * 256 + b_ * 16 + g_ * 4 + j_]);
    {
      const unsigned int* a = nullptr;
      if (isL2) {
        if (tid < 8) a = cnt1 + (size_t)t * 128 + tid * 16;
        else if (tid < 16 && t > 0) a = cnt2 + (size_t)(t - 1) * 128 + (tid - 8) * 16;
      } else if (t > 0 && tid < 8) {
        a = cnt1 + (size_t)(t - 1) * 128 + tid * 16;
      }
      if (a) {
        unsigned int gcount = 0;
        while (ldcnt(a) < 16u) {
          __builtin_amdgcn_s_sleep(2);
          if (++gcount > (1u << 16)) break;
        }
      }
    }
    __syncthreads();
    {
      int b = tid >> 4, k0 = (tid & 15) * 32;
      if (isL2) {
        const unsigned short* p = h1nB + (((size_t)t * 16 + b) << 9) + k0;
        float* d = &hs[b * LDHD + k0];
        float* d2 = &hs[b * LDHD + 512 + k0];
        if (t > 0) {
          const unsigned short* q = h2cB + (((size_t)(t - 1) * 16 + b) << 9) + k0;
          uivec4 a0, a1, a2, a3, a4, a5, a6, a7;
          ldg8_sc(p, p + 8, p + 16, p + 24, q, q + 8, q + 16, q + 24,
                  a0, a1, a2, a3, a4, a5, a6, a7);
          bf8_to_lds(d, a0); bf8_to_lds(d + 8, a1); bf8_to_lds(d + 16, a2); bf8_to_lds(d + 24, a3);
          bf8_to_lds(d2, a4); bf8_to_lds(d2 + 8, a5); bf8_to_lds(d2 + 16, a6); bf8_to_lds(d2 + 24, a7);
        } else {
          uivec4 a0, a1, a2, a3;
          ldg4_sc(p, p + 8, p + 16, p + 24, a0, a1, a2, a3);
          bf8_to_lds(d, a0); bf8_to_lds(d + 8, a1); bf8_to_lds(d + 16, a2); bf8_to_lds(d + 24, a3);
#pragma unroll
          for (int q2 = 0; q2 < 32; ++q2) d2[q2] = 0.0f;
        }
      } else if (t > 0) {
        const unsigned short* p = h1cB + (((size_t)(t - 1) * 16 + b) << 9) + k0;
        uivec4 a0, a1, a2, a3;
        ldg4_sc(p, p + 8, p + 16, p + 24, a0, a1, a2, a3);
        float* d = &hs[b * LDHD + k0];
        bf8_to_lds(d, a0); bf8_to_lds(d + 8, a1); bf8_to_lds(d + 16, a2); bf8_to_lds(d + 24, a3);
      }
    }
    __syncthreads();

    float acc[4][4];
#pragma unroll
    for (int a = 0; a < 4; ++a) { acc[a][0] = 0; acc[a][1] = 0; acc[a][2] = 0; acc[a][3] = 0; }
    const bool doDot = isL2 || (t > 0);
    if (doDot) {
      const int b0 = bq * 4;
      for (int i = 0; i < SEGI2; ++i) {
        int k2 = (i * 16 + s) * 2;
        float2 h0 = *(const float2*)&hs[(b0 + 0) * LDHD + k2];
        float2 h1 = *(const float2*)&hs[(b0 + 1) * LDHD + k2];
        float2 h2 = *(const float2*)&hs[(b0 + 2) * LDHD + k2];
        float2 h3 = *(const float2*)&hs[(b0 + 3) * LDHD + k2];
#pragma unroll
        for (int g = 0; g < 4; ++g) {
          float2 wv = *(const float2*)&wh[(g * 4 + jj) * LDHD + k2];
          acc[0][g] += h0.x * wv.x + h0.y * wv.y;
          acc[1][g] += h1.x * wv.x + h1.y * wv.y;
          acc[2][g] += h2.x * wv.x + h2.y * wv.y;
          acc[3][g] += h3.x * wv.x + h3.y * wv.y;
        }
      }
    }
#pragma unroll
    for (int a = 0; a < 4; ++a)
#pragma unroll
      for (int g = 0; g < 4; ++g)
        part[s * 257 + ((bq * 4 + a) * 16 + jj * 4 + g)] = acc[a][g];
    __syncthreads();
    {
      float sum = dxv;
      if (doDot) {
#pragma unroll
        for (int ss = 0; ss < 16; ++ss) sum += part[ss * 257 + tid];
      }
      gl[tid] = sum;
    }
    __syncthreads();
    if (tid < 64) {
      int b = tid >> 2, j = tid & 3;
      int colg = w * 4 + j;
      float gi = gl[b * 16 + j * 4 + 0];
      float gg = gl[b * 16 + j * 4 + 1];
      float gf = gl[b * 16 + j * 4 + 2];
      float go = gl[b * 16 + j * 4 + 3];
      float cold = (t == 0) ? 0.0f : cst[tid];
      float hold = (t == 0) ? 0.0f : hst[tid];
      float nc = sigm(gf + 1.0f) * cold + sigm(gi) * tanhf(gg);
      float nh = sigm(go) * tanhf(nc);
      size_t mi = ((size_t)b * 512 + t) * 512 + colg;
      bool mh = mask_at(zh, mi, mmode);
      bool mc = mask_at(zc, mi, mmode);
      cst[tid] = mc ? cold : nc;
      float hkeep = mh ? hold : nh;
      hst[tid] = hkeep;
      hN[(size_t)(t * 16 + b) * 512 + colg] = nh;  // plain f32, for k_proj
      stg_bf16(&hCB[(((size_t)t * 16 + b) << 9) + colg], hkeep);
      if (!isL2) stg_bf16(&h1nB[(((size_t)t * 16 + b) << 9) + colg], nh);
    }
    __syncthreads();
    if (tid == 0) {
      asm volatile("s_waitcnt vmcnt(0)" ::: "memory");
      __hip_atomic_fetch_add((isL2 ? cnt2 : cnt1) + (size_t)t * 128 + (w >> 4) * 16, 1u,
                             __ATOMIC_RELAXED, __HIP_MEMORY_SCOPE_AGENT);
    }
  }
}

// ---------------- projection ----------------
__global__ __launch_bounds__(320) void k_proj(const float* __restrict__ cond,
                                              const float* __restrict__ h1n,
                                              const float* __restrict__ h2n,
                                              const float* __restrict__ pw,
                                              const float* __restrict__ pb,
                                              float* __restrict__ mel) {
  __shared__ float as_[4 * 1536];
  int r0 = blockIdx.x * 4;
  for (int i = threadIdx.x; i < 4 * 1536; i += 320) {
    int row = i / 1536, k = i % 1536;
    int r = r0 + row;
    int b = r >> 9, t = r & 511;
    float v;
    if (k < 512) v = cond[(size_t)r * 512 + k];
    else if (k < 1024) v = h1n[(size_t)(t * 16 + b) * 512 + (k - 512)];
    else v = h2n[(size_t)(t * 16 + b) * 512 + (k - 1024)];
    as_[i] = v;
  }
  __syncthreads();
  int row = threadIdx.x / 80, co = threadIdx.x % 80;
  float acc = pb[co];
  for (int k = 0; k < 1536; ++k) acc += as_[row * 1536 + k] * pw[(size_t)k * 80 + co];
  mel[(size_t)(r0 + row) * 80 + co] = acc;
}

// ---------------- k=5 conv ----------------
__global__ __launch_bounds__(256) void k_conv5(const float* __restrict__ X, int Cin,
                                               float* __restrict__ Y, int Cout,
                                               const float* __restrict__ Wc,
                                               const float* __restrict__ bias) {
  extern __shared__ float ys[];
  int blk = blockIdx.x;
  int b = blk >> 6, t0 = (blk & 63) * 8;
  for (int i = threadIdx.x; i < 12 * Cin; i += 256) {
    int rr = i / Cin, ci = i % Cin;
    int tt = t0 - 2 + rr;
    ys[i] = (tt >= 0 && tt < 512) ? X[(size_t)(b * 512 + tt) * Cin + ci] : 0.0f;
  }
  __syncthreads();
  for (int co = threadIdx.x; co < Cout; co += 256) {
    float acc[8];
    float bv = bias ? bias[co] : 0.0f;
#pragma unroll
    for (int j = 0; j < 8; ++j) acc[j] = bv;
    for (int dt = 0; dt < 5; ++dt)
      for (int ci = 0; ci < Cin; ++ci) {
        float wv = Wc[(size_t)(dt * Cin + ci) * Cout + co];
#pragma unroll
        for (int j = 0; j < 8; ++j) acc[j] += ys[(j + dt) * Cin + ci] * wv;
      }
#pragma unroll
    for (int j = 0; j < 8; ++j) Y[(size_t)(b * 512 + t0 + j) * Cout + co] = acc[j];
  }
}

__global__ void k_out(const float* __restrict__ mel, const float* __restrict__ res,
                      void* __restrict__ out, const int* __restrict__ flags) {
  int i = blockIdx.x * 256 + threadIdx.x;
  float m = mel[i];
  float f = m + res[i];
  if (flags[0]) {
    ((float*)out)[i] = m;
    ((float*)out)[655360 + i] = f;
  } else {
    unsigned short* o = (unsigned short*)out;
    o[i] = f2b(m);
    o[655360 + i] = f2b(f);
  }
}

// ---------------- host launch ----------------
extern "C" void kernel_launch(void* const* d_in, const int* in_sizes, int n_in,
                              void* d_out, int out_size, void* d_ws, size_t ws_size,
                              hipStream_t stream) {
  char* ws = (char*)d_ws;
  size_t o = 0;
  auto A_ = [&](size_t nb) { size_t r = o; o += (nb + 255) & ~(size_t)255; return r; };
  const size_t FLAGS = A_(256);
  const size_t SYNC = A_(786432);
  const size_t STATS = A_(4096);
  const size_t C_MELS = A_(655360ull * 4), C_DUR = A_(4096 * 4), C_EMB = A_(65536 * 4),
               C_ECW = A_(589824ull * 4), C_EBS = A_(768 * 4), C_EBO = A_(768 * 4),
               C_LFW = A_(524288ull * 4), C_LFB = A_(1024 * 4), C_LBW = A_(524288ull * 4),
               C_LBB = A_(1024 * 4), C_PW1 = A_(20480 * 4), C_P1S = A_(256 * 4),
               C_P1O = A_(256 * 4), C_PW2 = A_(65536 * 4), C_P2S = A_(256 * 4),
               C_P2O = A_(256 * 4), C_DW1 = A_(2621440ull * 4), C_DB1 = A_(2048 * 4),
               C_DW2 = A_(3670016ull * 4), C_DB2 = A_(2048 * 4), C_PRW = A_(122880ull * 4),
               C_PRB = A_(512), C_W0 = A_(204800ull * 4), C_WM = A_(3932160ull * 4),
               C_W4 = A_(204800ull * 4), C_B4 = A_(512), C_PBS = A_(2048 * 4),
               C_PBO = A_(2048 * 4);
  const size_t R1 = A_(16777216), R2 = A_(16777216), R3 = A_(16777216), R4 = A_(16777216),
               MID = A_(4096 * 4), R5 = A_(16777216), R6 = A_(16777216), R7 = A_(25165824),
               D1X = A_(33554432), D2X = A_(33554432), MELP = A_(2621440);
  const size_t XA = R1, XB = R1 + 4194304;
  const size_t GF = R2;
  const size_t GB = R3, H1N = R3;
  const size_t ENC = R4, H2N = R4;
  const size_t COND = R5, PA = R5;
  const size_t PREA = R6, PREB = R6 + 8388608, PB = R6;
  const size_t DECIN = R7, RESID = R7;
  // bf16 broadcast buffers (intra-kernel only; read via sc0/sc1 bypass -> alias-safe)
  const size_t H1CB = R1, H1NB = R1 + 8388608;  // decoder phase: R1 free
  const size_t H2CB = R2;                       // decoder phase: R2 free
  const size_t ENCB = R7;                       // encoder phase: R7 untouched until concat

  auto F = [&](size_t off) { return (float*)(ws + off); };
  auto U = [&](size_t off) { return (unsigned short*)(ws + off); };
  int* flags = (int*)(ws + FLAGS);
  unsigned int* cntE = (unsigned int*)(ws + SYNC);
  unsigned int* cnt1 = (unsigned int*)(ws + SYNC + 262144);
  unsigned int* cnt2 = (unsigned int*)(ws + SYNC + 524288);

  hipMemsetAsync(ws + SYNC, 0, 786432, stream);
  k_detect<<<1, 256, 0, stream>>>(d_in[8], d_in[4], flags);

  struct CV { int idx; size_t off; int n; };
  const CV cvs[] = {
      {2, C_MELS, 655360}, {3, C_DUR, 4096}, {8, C_EMB, 65536}, {9, C_ECW, 589824},
      {10, C_EBS, 768}, {11, C_EBO, 768}, {12, C_LFW, 524288}, {13, C_LFB, 1024},
      {14, C_LBW, 524288}, {15, C_LBB, 1024}, {16, C_PW1, 20480}, {17, C_P1S, 256},
      {18, C_P1O, 256}, {19, C_PW2, 65536}, {20, C_P2S, 256}, {21, C_P2O, 256},
      {22, C_DW1, 2621440}, {23, C_DB1, 2048}, {24, C_DW2, 3670016}, {25, C_DB2, 2048},
      {26, C_PRW, 122880}, {27, C_PRB, 80}, {28, C_W0, 204800}, {29, C_WM, 3932160},
      {30, C_W4, 204800}, {31, C_B4, 80}, {32, C_PBS, 2048}, {33, C_PBO, 2048}};
  for (int i = 0; i < (int)(sizeof(cvs) / sizeof(cvs[0])); ++i)
    k_cvt<<<(cvs[i].n + 255) / 256, 256, 0, stream>>>(d_in[cvs[i].idx], F(cvs[i].off), cvs[i].n, flags);

  k_embed<<<4096, 256, 0, stream>>>((const int*)d_in[0], F(C_EMB), F(XA));
  for (int i = 0; i < 3; ++i) {
    k_conv3<<<1024, 256, 0, stream>>>(F(XA), F(C_ECW) + (size_t)i * 196608, F(XB));
    k_colstats<<<256, 256, 0, stream>>>(F(XB), 4096, 256, F(STATS));
    k_bnact<0><<<4096, 256, 0, stream>>>(F(XB), F(XA), F(STATS), F(C_EBS) + i * 256, F(C_EBO) + i * 256, 255, 1048576);
  }
  k_gemm<3><<<dim3(256, 4), 256, 0, stream>>>(F(XA), F(C_LFW), F(C_LFB), (void*)(ws + GF), 4096, 256, 1024);
  k_gemm<3><<<dim3(256, 4), 256, 0, stream>>>(F(XA), F(C_LBW), F(C_LBB), (void*)(ws + GB), 4096, 256, 1024);
  k_cumsum<<<1, 64, 0, stream>>>(F(C_DUR), F(MID));
  k_enc_lstm<<<128, 256, 0, stream>>>(F(GF), F(GB), F(C_LFW), F(C_LBW), F(ENC), U(ENCB),
                                      (const int*)d_in[1], cntE);
  k_upsample<<<512, 256, 0, stream>>>(F(MID), F(ENC), F(COND));

  k_gemm<0><<<dim3(512, 1), 256, 0, stream>>>(F(C_MELS), F(C_PW1), nullptr, (void*)(ws + PREA), 8192, 80, 256);
  k_colstats<<<256, 256, 0, stream>>>(F(PREA), 8192, 256, F(STATS));
  k_bnact<0><<<8192, 256, 0, stream>>>(F(PREA), F(PREB), F(STATS), F(C_P1S), F(C_P1O), 255, 2097152);
  k_gemm<0><<<dim3(512, 1), 256, 0, stream>>>(F(PREB), F(C_PW2), nullptr, (void*)(ws + PREA), 8192, 256, 256);
  k_colstats<<<256, 256, 0, stream>>>(F(PREA), 8192, 256, F(STATS));
  k_bnact<0><<<8192, 256, 0, stream>>>(F(PREA), F(PREB), F(STATS), F(C_P2S), F(C_P2O), 255, 2097152);

  k_concat<<<24576, 256, 0, stream>>>(F(COND), F(PREB), F(DECIN));
  k_gemm<2><<<dim3(512, 8), 256, 0, stream>>>(F(DECIN), F(C_DW1), F(C_DB1), (void*)(ws + D1X), 8192, 768, 2048);
  k_gemm<2><<<dim3(512, 8), 256, 0, stream>>>(F(DECIN), F(C_DW2), F(C_DB2), (void*)(ws + D2X), 8192, 768, 2048);
  k_dec_lstm<<<256, 256, 0, stream>>>((const unsigned short*)(ws + D1X), (const unsigned short*)(ws + D2X),
                                      F(C_DW1), F(C_DW2), d_in[4], d_in[5], d_in[6], d_in[7],
                                      U(H1CB), U(H1NB), U(H2CB),
                                      F(H1N), F(H2N), cnt1, cnt2, flags);
  k_proj<<<2048, 320, 0, stream>>>(F(COND), F(H1N), F(H2N), F(C_PRW), F(C_PRB), F(MELP));

  k_conv5<<<1024, 256, 12 * 80 * 4, stream>>>(F(MELP), 80, F(PA), 512, F(C_W0), nullptr);
  k_colstats<<<512, 256, 0, stream>>>(F(PA), 8192, 512, F(STATS));
  k_bnact<1><<<16384, 256, 0, stream>>>(F(PA), F(PB), F(STATS), F(C_PBS), F(C_PBO), 511, 4194304);
  for (int i = 0; i < 3; ++i) {
    k_conv5<<<1024, 256, 12 * 512 * 4, stream>>>(F(PB), 512, F(PA), 512, F(C_WM) + (size_t)i * 1310720, nullptr);
    k_colstats<<<512, 256, 0, stream>>>(F(PA), 8192, 512, F(STATS));
    k_bnact<1><<<16384, 256, 0, stream>>>(F(PA), F(PB), F(STATS), F(C_PBS) + (i + 1) * 512, F(C_PBO) + (i + 1) * 512, 511, 4194304);
  }
  k_conv5<<<1024, 256, 12 * 512 * 4, stream>>>(F(PB), 512, F(RESID), 80, F(C_W4), F(C_B4));
  k_out<<<2560, 256, 0, stream>>>(F(MELP), F(RESID), d_out, flags);
}